// Round 2
// baseline (894.889 us; speedup 1.0000x reference)
//
#include <hip/hip_runtime.h>
#include <math.h>

#define D 30
#define BKT 128                 // destination nodes per bucket
#define LGB 7                   // log2(BKT)
#define CHUNK 8192              // edges per binning block
#define ROWBITS 18
#define ROWMASK ((1u << ROWBITS) - 1)

// ---------------- Kernel A: degree atomics + bucket histogram ----------------
__global__ __launch_bounds__(256) void deg_hist_kernel(const int* __restrict__ col,
                                                       const float* __restrict__ ew,
                                                       float* __restrict__ deg,
                                                       unsigned* __restrict__ hist,
                                                       int E, int nbkt) {
    __shared__ unsigned lh[1024];
    const int t = threadIdx.x;
    for (int i = t; i < nbkt; i += 256) lh[i] = 0;
    __syncthreads();
    const int stride = gridDim.x * 256;
    for (int e = blockIdx.x * 256 + t; e < E; e += stride) {
        const int c = col[e];
        atomicAdd(&deg[c], ew[e]);
        atomicAdd(&lh[c >> LGB], 1u);
    }
    __syncthreads();
    for (int i = t; i < nbkt; i += 256) {
        const unsigned v = lh[i];
        if (v) atomicAdd(&hist[i], v);
    }
}

// ---------------- Kernel B: exclusive scan of bucket counts ----------------
__global__ __launch_bounds__(1024) void scan_kernel(const unsigned* __restrict__ hist,
                                                    unsigned* __restrict__ base,
                                                    unsigned* __restrict__ cursor,
                                                    int nbkt) {
    __shared__ unsigned s[1024];
    const int t = threadIdx.x;
    const unsigned v = (t < nbkt) ? hist[t] : 0u;
    s[t] = v;
    for (int off = 1; off < 1024; off <<= 1) {
        __syncthreads();
        const unsigned x = (t >= off) ? s[t - off] : 0u;
        __syncthreads();
        s[t] += x;
    }
    __syncthreads();
    if (t < nbkt) {
        const unsigned excl = s[t] - v;
        base[t] = excl;
        cursor[t] = excl;
        if (t == nbkt - 1) base[nbkt] = s[t];
    }
}

// ---------------- Kernel C: x = h@W; y = x * rsqrt(deg+1) ----------------
__global__ __launch_bounds__(256) void gemm_kernel(const float* __restrict__ h,
                                                   const float* __restrict__ W,
                                                   const float* __restrict__ deg,
                                                   float* __restrict__ dis,
                                                   float* __restrict__ y, int N) {
    __shared__ float hs[256 * D];
    __shared__ float Ws[D * D];
    const int t = threadIdx.x;
    const int nb = blockIdx.x * 256;
    const int cnt = min(256, N - nb);
    const int total = cnt * D;

    for (int i = t; i < D * D; i += 256) Ws[i] = W[i];
    for (int i = t; i < total; i += 256) hs[i] = h[nb * D + i];
    __syncthreads();

    if (t < cnt) {
        const int n = nb + t;
        float x[D];
#pragma unroll
        for (int j = 0; j < D; ++j) x[j] = 0.f;
#pragma unroll
        for (int k = 0; k < D; ++k) {
            const float hv = hs[t * D + k];
#pragma unroll
            for (int j = 0; j < D; ++j) x[j] += hv * Ws[k * D + j];
        }
        const float dv = rsqrtf(deg[n] + 1.0f);  // +1 = self-loop weight
        dis[n] = dv;
#pragma unroll
        for (int j = 0; j < D; ++j) hs[t * D + j] = x[j] * dv;  // own row only
    }
    __syncthreads();

    for (int i = t; i < total; i += 256) y[nb * D + i] = hs[i];
}

// ---------------- Kernel D: bin edges by destination bucket ----------------
__global__ __launch_bounds__(256) void binscatter_kernel(const int* __restrict__ row,
                                                         const int* __restrict__ col,
                                                         const float* __restrict__ ew,
                                                         unsigned* __restrict__ cursor,
                                                         uint2* __restrict__ keysw,
                                                         int E, int nbkt) {
    __shared__ unsigned lh[1024];
    const int t = threadIdx.x;
    const int e0 = blockIdx.x * CHUNK;
    const int e1 = min(e0 + CHUNK, E);
    for (int i = t; i < nbkt; i += 256) lh[i] = 0;
    __syncthreads();
    for (int e = e0 + t; e < e1; e += 256) atomicAdd(&lh[col[e] >> LGB], 1u);
    __syncthreads();
    for (int i = t; i < nbkt; i += 256) {
        const unsigned c = lh[i];
        if (c) lh[i] = atomicAdd(&cursor[i], c);
    }
    __syncthreads();
    for (int e = e0 + t; e < e1; e += 256) {
        const int c = col[e];
        const int b = c >> LGB;
        const unsigned slot = atomicAdd(&lh[b], 1u);
        keysw[slot] = make_uint2(((unsigned)(c & (BKT - 1)) << ROWBITS) | (unsigned)row[e],
                                 __float_as_uint(ew[e]));
    }
}

// ---------------- Kernel E: LDS aggregation + fused MLP ----------------
__global__ __launch_bounds__(512) void aggmlp_kernel(const float* __restrict__ y,
                                                     const float* __restrict__ dis,
                                                     const unsigned* __restrict__ base,
                                                     const uint2* __restrict__ keysw,
                                                     const float* __restrict__ convb,
                                                     const float* __restrict__ w1,
                                                     const float* __restrict__ b1,
                                                     const float* __restrict__ w2,
                                                     const float* __restrict__ b2,
                                                     const float* __restrict__ w3,
                                                     const float* __restrict__ b3,
                                                     const float* __restrict__ w4,
                                                     const float* __restrict__ b4,
                                                     float* __restrict__ out, int N) {
    __shared__ float acc[BKT * D];
    __shared__ float cb[D];
    __shared__ float W1[300], B1[10], W2[100], B2[10], W3[100], B3[10], W4[10], B4v[1];
    const int t = threadIdx.x;
    if (t < D) cb[t] = convb[t];
    for (int i = t; i < 300; i += 512) W1[i] = w1[i];
    if (t < 100) W2[t] = w2[t];
    if (t >= 128 && t < 228) W3[t - 128] = w3[t - 128];
    if (t < 10) { B1[t] = b1[t]; B2[t] = b2[t]; B3[t] = b3[t]; W4[t] = w4[t]; }
    if (t == 0) B4v[0] = b4[0];

    const int b = blockIdx.x;
    const int nb = b * BKT;
    const int cnt = min(BKT, N - nb);
    for (int i = t; i < cnt * D; i += 512) acc[i] = y[nb * D + i];  // self-loop init
    __syncthreads();

    const unsigned e0 = base[b], e1 = base[b + 1];
    const int m = (int)(e1 - e0) * 32;
    for (int i = t; i < m; i += 512) {
        const unsigned e = e0 + (unsigned)(i >> 5);
        const int d = i & 31;
        const uint2 kw = keysw[e];
        if (d < D) {
            const unsigned rowv = kw.x & ROWMASK;
            const unsigned local = kw.x >> ROWBITS;
            const float w = __uint_as_float(kw.y);
            atomicAdd(&acc[local * D + d], y[rowv * D + d] * w);
        }
    }
    __syncthreads();

    if (t < cnt) {
        const int n = nb + t;
        const float dv = dis[n];
        float v[D];
#pragma unroll
        for (int j = 0; j < D; ++j) v[j] = fmaxf(dv * acc[t * D + j] + cb[j], 0.f);
        float h1[10];
#pragma unroll
        for (int j = 0; j < 10; ++j) h1[j] = B1[j];
#pragma unroll
        for (int k = 0; k < D; ++k) {
            const float vv = v[k];
#pragma unroll
            for (int j = 0; j < 10; ++j) h1[j] += vv * W1[k * 10 + j];
        }
#pragma unroll
        for (int j = 0; j < 10; ++j) h1[j] = fmaxf(h1[j], 0.f);
        float h2[10];
#pragma unroll
        for (int j = 0; j < 10; ++j) h2[j] = B2[j];
#pragma unroll
        for (int k = 0; k < 10; ++k) {
            const float vv = h1[k];
#pragma unroll
            for (int j = 0; j < 10; ++j) h2[j] += vv * W2[k * 10 + j];
        }
#pragma unroll
        for (int j = 0; j < 10; ++j) h2[j] = fmaxf(h2[j], 0.f);
        float h3[10];
#pragma unroll
        for (int j = 0; j < 10; ++j) h3[j] = B3[j];
#pragma unroll
        for (int k = 0; k < 10; ++k) {
            const float vv = h2[k];
#pragma unroll
            for (int j = 0; j < 10; ++j) h3[j] += vv * W3[k * 10 + j];
        }
#pragma unroll
        for (int j = 0; j < 10; ++j) h3[j] = fmaxf(h3[j], 0.f);
        float z = B4v[0];
#pragma unroll
        for (int k = 0; k < 10; ++k) z += h3[k] * W4[k];
        out[n] = 1.f / (1.f + expf(-z));
    }
}

extern "C" void kernel_launch(void* const* d_in, const int* in_sizes, int n_in,
                              void* d_out, int out_size, void* d_ws, size_t ws_size,
                              hipStream_t stream) {
    const float* h   = (const float*)d_in[0];
    const int*   ei  = (const int*)d_in[1];   // [2, E]: row = ei[0:E], col = ei[E:2E]
    const float* ew  = (const float*)d_in[2];
    const float* convW = (const float*)d_in[3];
    const float* convb = (const float*)d_in[4];
    const float* w1 = (const float*)d_in[5];
    const float* b1 = (const float*)d_in[6];
    const float* w2 = (const float*)d_in[7];
    const float* b2 = (const float*)d_in[8];
    const float* w3 = (const float*)d_in[9];
    const float* b3 = (const float*)d_in[10];
    const float* w4 = (const float*)d_in[11];
    const float* b4 = (const float*)d_in[12];
    float* out = (float*)d_out;

    const int N = in_sizes[0] / D;
    const int E = in_sizes[2];
    const int* row = ei;
    const int* col = ei + E;
    const int nbkt = (N + BKT - 1) >> LGB;          // 782 for N=100000
    const int nchunks = (E + CHUNK - 1) / CHUNK;    // 391
    const int nblocks = (N + 255) / 256;            // 391

    // workspace layout: keysw[E] (uint2) | deg[N] | dis[N] | y[N*D] | hist | base | cursor
    uint2* keysw = (uint2*)d_ws;
    float* deg = (float*)(keysw + E);
    float* dis = deg + N;
    float* y   = dis + N;
    unsigned* hist   = (unsigned*)(y + (size_t)N * D);
    unsigned* base   = hist + nbkt;
    unsigned* cursor = base + nbkt + 1;

    hipMemsetAsync(deg, 0, (size_t)N * sizeof(float), stream);
    hipMemsetAsync(hist, 0, (size_t)nbkt * sizeof(unsigned), stream);

    deg_hist_kernel<<<512, 256, 0, stream>>>(col, ew, deg, hist, E, nbkt);
    scan_kernel<<<1, 1024, 0, stream>>>(hist, base, cursor, nbkt);
    gemm_kernel<<<nblocks, 256, 0, stream>>>(h, convW, deg, dis, y, N);
    binscatter_kernel<<<nchunks, 256, 0, stream>>>(row, col, ew, cursor, keysw, E, nbkt);
    aggmlp_kernel<<<nbkt, 512, 0, stream>>>(y, dis, base, keysw, convb,
                                            w1, b1, w2, b2, w3, b3, w4, b4, out, N);
}

// Round 3
// 872.561 us; speedup vs baseline: 1.0256x; 1.0256x over previous
//
#include <hip/hip_runtime.h>
#include <hip/hip_fp16.h>
#include <math.h>

#define D 30
#define BKT 64                  // destination nodes per bucket
#define LGB 6                   // log2(BKT)
#define CHUNK 8192              // edges per binning block
#define ROWBITS 18
#define ROWMASK ((1u << ROWBITS) - 1)
#define MAXBKT 2048

// ---------------- Kernel A: degree atomics + bucket histogram ----------------
__global__ __launch_bounds__(256) void deg_hist_kernel(const int* __restrict__ col,
                                                       const float* __restrict__ ew,
                                                       float* __restrict__ deg,
                                                       unsigned* __restrict__ hist,
                                                       int E, int nbkt) {
    __shared__ unsigned lh[MAXBKT];
    const int t = threadIdx.x;
    for (int i = t; i < nbkt; i += 256) lh[i] = 0;
    __syncthreads();
    const int stride = gridDim.x * 256;
    for (int e = blockIdx.x * 256 + t; e < E; e += stride) {
        const int c = col[e];
        atomicAdd(&deg[c], ew[e]);
        atomicAdd(&lh[c >> LGB], 1u);
    }
    __syncthreads();
    for (int i = t; i < nbkt; i += 256) {
        const unsigned v = lh[i];
        if (v) atomicAdd(&hist[i], v);
    }
}

// ---------------- Kernel B: exclusive scan of bucket counts (multi-tile) ----------------
__global__ __launch_bounds__(1024) void scan_kernel(const unsigned* __restrict__ hist,
                                                    unsigned* __restrict__ base,
                                                    unsigned* __restrict__ cursor,
                                                    int nbkt) {
    __shared__ unsigned s[1024];
    __shared__ unsigned carry_s;
    const int t = threadIdx.x;
    if (t == 0) carry_s = 0;
    const int ntiles = (nbkt + 1023) >> 10;
    for (int tile = 0; tile < ntiles; ++tile) {
        const int idx = (tile << 10) + t;
        const unsigned v = (idx < nbkt) ? hist[idx] : 0u;
        __syncthreads();           // prev tile fully done with s/carry_s
        s[t] = v;
        for (int off = 1; off < 1024; off <<= 1) {
            __syncthreads();
            const unsigned x = (t >= off) ? s[t - off] : 0u;
            __syncthreads();
            s[t] += x;
        }
        __syncthreads();
        const unsigned carry = carry_s;
        const unsigned excl = carry + s[t] - v;
        if (idx < nbkt) { base[idx] = excl; cursor[idx] = excl; }
        if (idx == nbkt - 1) base[nbkt] = excl + v;
        __syncthreads();
        if (t == 1023) carry_s = carry + s[1023];
    }
}

// ---------------- Kernel C: x = h@W; yp = half(x * rsqrt(deg+1)), padded to 32 ----------------
__global__ __launch_bounds__(256) void gemm_kernel(const float* __restrict__ h,
                                                   const float* __restrict__ W,
                                                   const float* __restrict__ deg,
                                                   float* __restrict__ dis,
                                                   uint4* __restrict__ yp4, int N) {
    __shared__ float hs[256 * D];
    __shared__ float Ws[D * D];
    const int t = threadIdx.x;
    const int nb = blockIdx.x * 256;
    const int cnt = min(256, N - nb);
    const int total = cnt * D;

    for (int i = t; i < D * D; i += 256) Ws[i] = W[i];
    for (int i = t; i < total; i += 256) hs[i] = h[nb * D + i];
    __syncthreads();

    float x[D];
    float dv = 0.f;
    if (t < cnt) {
        const int n = nb + t;
#pragma unroll
        for (int j = 0; j < D; ++j) x[j] = 0.f;
#pragma unroll
        for (int k = 0; k < D; ++k) {
            const float hv = hs[t * D + k];
#pragma unroll
            for (int j = 0; j < D; ++j) x[j] += hv * Ws[k * D + j];
        }
        dv = rsqrtf(deg[n] + 1.0f);  // +1 = self-loop weight
        dis[n] = dv;
    }
    __syncthreads();             // everyone done reading hs
    __half* hsh = (__half*)hs;   // reuse LDS as half[256][32]
    if (t < cnt) {
#pragma unroll
        for (int j = 0; j < D; ++j) hsh[t * 32 + j] = __float2half_rn(x[j] * dv);
        hsh[t * 32 + 30] = __float2half_rn(0.f);
        hsh[t * 32 + 31] = __float2half_rn(0.f);
    }
    __syncthreads();
    const uint4* hv4 = (const uint4*)hs;
    for (int i = t; i < cnt * 4; i += 256) yp4[nb * 4 + i] = hv4[i];
}

// ---------------- Kernel D: bin edges by destination bucket ----------------
__global__ __launch_bounds__(256) void binscatter_kernel(const int* __restrict__ row,
                                                         const int* __restrict__ col,
                                                         const float* __restrict__ ew,
                                                         unsigned* __restrict__ cursor,
                                                         uint2* __restrict__ keysw,
                                                         int E, int nbkt) {
    __shared__ unsigned lh[MAXBKT];
    const int t = threadIdx.x;
    const int e0 = blockIdx.x * CHUNK;
    const int e1 = min(e0 + CHUNK, E);
    for (int i = t; i < nbkt; i += 256) lh[i] = 0;
    __syncthreads();
    for (int e = e0 + t; e < e1; e += 256) atomicAdd(&lh[col[e] >> LGB], 1u);
    __syncthreads();
    for (int i = t; i < nbkt; i += 256) {
        const unsigned c = lh[i];
        if (c) lh[i] = atomicAdd(&cursor[i], c);
    }
    __syncthreads();
    for (int e = e0 + t; e < e1; e += 256) {
        const int c = col[e];
        const int b = c >> LGB;
        const unsigned slot = atomicAdd(&lh[b], 1u);
        keysw[slot] = make_uint2(((unsigned)(c & (BKT - 1)) << ROWBITS) | (unsigned)row[e],
                                 __float_as_uint(ew[e]));
    }
}

// ---------------- Kernel E: LDS aggregation (fp16 gather) + fused MLP ----------------
__global__ __launch_bounds__(512) void aggmlp_kernel(const __half* __restrict__ yp,
                                                     const uint4* __restrict__ yp4,
                                                     const float* __restrict__ dis,
                                                     const unsigned* __restrict__ base,
                                                     const uint2* __restrict__ keysw,
                                                     const float* __restrict__ convb,
                                                     const float* __restrict__ w1,
                                                     const float* __restrict__ b1,
                                                     const float* __restrict__ w2,
                                                     const float* __restrict__ b2,
                                                     const float* __restrict__ w3,
                                                     const float* __restrict__ b3,
                                                     const float* __restrict__ w4,
                                                     const float* __restrict__ b4,
                                                     float* __restrict__ out, int N) {
    __shared__ float acc[BKT * 32];
    __shared__ float cb[D];
    __shared__ float W1[300], B1[10], W2[100], B2[10], W3[100], B3[10], W4[10], B4v[1];
    const int t = threadIdx.x;
    if (t < D) cb[t] = convb[t];
    for (int i = t; i < 300; i += 512) W1[i] = w1[i];
    if (t < 100) W2[t] = w2[t];
    if (t >= 128 && t < 228) W3[t - 128] = w3[t - 128];
    if (t < 10) { B1[t] = b1[t]; B2[t] = b2[t]; B3[t] = b3[t]; W4[t] = w4[t]; }
    if (t == 0) B4v[0] = b4[0];

    const int b = blockIdx.x;
    const int nb = b * BKT;
    const int cnt = min(BKT, N - nb);
    // self-loop init (swizzled layout)
    for (int i = t; i < cnt * 32; i += 512) {
        const int n = i >> 5, w = i & 31;
        acc[(n << 5) + (w ^ ((n & 7) << 2))] =
            __half2float(yp[(size_t)(nb + n) * 32 + w]);
    }
    __syncthreads();

    const unsigned e0v = base[b], e1v = base[b + 1];
    const int m = (int)(e1v - e0v) * 4;   // 4 lanes per edge

#define PROCQ(v, q, loc, wgt)                                                        \
    {                                                                                \
        const __half2* hh = (const __half2*)&(v);                                    \
        const int wb = (q) << 3;                                                     \
        const int sw = ((loc) & 7) << 2;                                             \
        const int bo = (int)(loc) << 5;                                              \
        float2 f0 = __half22float2(hh[0]);                                           \
        float2 f1 = __half22float2(hh[1]);                                           \
        float2 f2 = __half22float2(hh[2]);                                           \
        float2 f3 = __half22float2(hh[3]);                                           \
        atomicAdd(&acc[bo + ((wb + 0) ^ sw)], f0.x * (wgt));                         \
        atomicAdd(&acc[bo + ((wb + 1) ^ sw)], f0.y * (wgt));                         \
        atomicAdd(&acc[bo + ((wb + 2) ^ sw)], f1.x * (wgt));                         \
        atomicAdd(&acc[bo + ((wb + 3) ^ sw)], f1.y * (wgt));                         \
        atomicAdd(&acc[bo + ((wb + 4) ^ sw)], f2.x * (wgt));                         \
        atomicAdd(&acc[bo + ((wb + 5) ^ sw)], f2.y * (wgt));                         \
        atomicAdd(&acc[bo + ((wb + 6) ^ sw)], f3.x * (wgt));                         \
        atomicAdd(&acc[bo + ((wb + 7) ^ sw)], f3.y * (wgt));                         \
    }

    for (int i = t; i < m; i += 1024) {
        const int iB = i + 512;
        const bool hasB = iB < m;
        const uint2 kwA = keysw[e0v + (unsigned)(i >> 2)];
        uint2 kwB = kwA;
        if (hasB) kwB = keysw[e0v + (unsigned)(iB >> 2)];
        const int qA = i & 3;
        const unsigned rowA = kwA.x & ROWMASK;
        const unsigned locA = kwA.x >> ROWBITS;
        const float wA = __uint_as_float(kwA.y);
        const uint4 vA = yp4[rowA * 4 + qA];
        if (hasB) {
            const int qB = iB & 3;
            const unsigned rowB = kwB.x & ROWMASK;
            const unsigned locB = kwB.x >> ROWBITS;
            const float wB = __uint_as_float(kwB.y);
            const uint4 vB = yp4[rowB * 4 + qB];
            PROCQ(vA, qA, locA, wA);
            PROCQ(vB, qB, locB, wB);
        } else {
            PROCQ(vA, qA, locA, wA);
        }
    }
    __syncthreads();

    if (t < cnt) {
        const int n = nb + t;
        const float dv = dis[n];
        const int bo = t << 5;
        const int sw = (t & 7) << 2;
        float v[D];
#pragma unroll
        for (int j = 0; j < D; ++j) v[j] = fmaxf(dv * acc[bo + (j ^ sw)] + cb[j], 0.f);
        float h1[10];
#pragma unroll
        for (int j = 0; j < 10; ++j) h1[j] = B1[j];
#pragma unroll
        for (int k = 0; k < D; ++k) {
            const float vv = v[k];
#pragma unroll
            for (int j = 0; j < 10; ++j) h1[j] += vv * W1[k * 10 + j];
        }
#pragma unroll
        for (int j = 0; j < 10; ++j) h1[j] = fmaxf(h1[j], 0.f);
        float h2[10];
#pragma unroll
        for (int j = 0; j < 10; ++j) h2[j] = B2[j];
#pragma unroll
        for (int k = 0; k < 10; ++k) {
            const float vv = h1[k];
#pragma unroll
            for (int j = 0; j < 10; ++j) h2[j] += vv * W2[k * 10 + j];
        }
#pragma unroll
        for (int j = 0; j < 10; ++j) h2[j] = fmaxf(h2[j], 0.f);
        float h3[10];
#pragma unroll
        for (int j = 0; j < 10; ++j) h3[j] = B3[j];
#pragma unroll
        for (int k = 0; k < 10; ++k) {
            const float vv = h2[k];
#pragma unroll
            for (int j = 0; j < 10; ++j) h3[j] += vv * W3[k * 10 + j];
        }
#pragma unroll
        for (int j = 0; j < 10; ++j) h3[j] = fmaxf(h3[j], 0.f);
        float z = B4v[0];
#pragma unroll
        for (int k = 0; k < 10; ++k) z += h3[k] * W4[k];
        out[n] = 1.f / (1.f + expf(-z));
    }
}

extern "C" void kernel_launch(void* const* d_in, const int* in_sizes, int n_in,
                              void* d_out, int out_size, void* d_ws, size_t ws_size,
                              hipStream_t stream) {
    const float* h   = (const float*)d_in[0];
    const int*   ei  = (const int*)d_in[1];   // [2, E]: row = ei[0:E], col = ei[E:2E]
    const float* ew  = (const float*)d_in[2];
    const float* convW = (const float*)d_in[3];
    const float* convb = (const float*)d_in[4];
    const float* w1 = (const float*)d_in[5];
    const float* b1 = (const float*)d_in[6];
    const float* w2 = (const float*)d_in[7];
    const float* b2 = (const float*)d_in[8];
    const float* w3 = (const float*)d_in[9];
    const float* b3 = (const float*)d_in[10];
    const float* w4 = (const float*)d_in[11];
    const float* b4 = (const float*)d_in[12];
    float* out = (float*)d_out;

    const int N = in_sizes[0] / D;
    const int E = in_sizes[2];
    const int* row = ei;
    const int* col = ei + E;
    const int nbkt = (N + BKT - 1) >> LGB;          // 1563 for N=100000
    const int nchunks = (E + CHUNK - 1) / CHUNK;    // 391
    const int nblocks = (N + 255) / 256;            // 391

    // workspace: yp[N*32 half] | keysw[E uint2] | deg[N] | dis[N] | hist | base | cursor
    __half* yp = (__half*)d_ws;
    uint2* keysw = (uint2*)(yp + (size_t)N * 32);
    float* deg = (float*)(keysw + E);
    float* dis = deg + N;
    unsigned* hist   = (unsigned*)(dis + N);
    unsigned* base   = hist + nbkt;
    unsigned* cursor = base + nbkt + 1;

    hipMemsetAsync(deg, 0, (size_t)N * sizeof(float), stream);
    hipMemsetAsync(hist, 0, (size_t)nbkt * sizeof(unsigned), stream);

    deg_hist_kernel<<<1024, 256, 0, stream>>>(col, ew, deg, hist, E, nbkt);
    scan_kernel<<<1, 1024, 0, stream>>>(hist, base, cursor, nbkt);
    gemm_kernel<<<nblocks, 256, 0, stream>>>(h, convW, deg, dis, (uint4*)yp, N);
    binscatter_kernel<<<nchunks, 256, 0, stream>>>(row, col, ew, cursor, keysw, E, nbkt);
    aggmlp_kernel<<<nbkt, 512, 0, stream>>>(yp, (const uint4*)yp, dis, base, keysw, convb,
                                            w1, b1, w2, b2, w3, b3, w4, b4, out, N);
}

// Round 4
// 504.987 us; speedup vs baseline: 1.7721x; 1.7279x over previous
//
#include <hip/hip_runtime.h>
#include <hip/hip_fp16.h>
#include <math.h>

#define D 30
#define FIXS 16777216.0f   // 2^24 fixed-point scale for degree weights

// ---------------- Kernel A: fused count|fixdeg u64 histogram (native atomic) ----------------
__global__ __launch_bounds__(256) void hist_kernel(const int* __restrict__ col,
                                                   const float* __restrict__ ew,
                                                   unsigned long long* __restrict__ cd,
                                                   int E) {
    const int stride = gridDim.x * 256;
    for (int e = blockIdx.x * 256 + threadIdx.x; e < E; e += stride) {
        const unsigned fix = (unsigned)(ew[e] * FIXS);
        atomicAdd(&cd[col[e]], (1ull << 32) | (unsigned long long)fix);
    }
}

// ---------------- Scan step A: per-1024-tile exclusive scan ----------------
__global__ __launch_bounds__(1024) void scanA_kernel(const unsigned long long* __restrict__ cd,
                                                     unsigned* __restrict__ base,
                                                     unsigned* __restrict__ psum, int N) {
    __shared__ unsigned s[1024];
    const int t = threadIdx.x;
    const int i = blockIdx.x * 1024 + t;
    const unsigned v = (i < N) ? (unsigned)(cd[i] >> 32) : 0u;
    s[t] = v;
    for (int off = 1; off < 1024; off <<= 1) {
        __syncthreads();
        const unsigned x = (t >= off) ? s[t - off] : 0u;
        __syncthreads();
        s[t] += x;
    }
    __syncthreads();
    if (i < N) base[i] = s[t] - v;
    if (t == 1023) psum[blockIdx.x] = s[1023];
}

// ---------------- Scan step B: exclusive scan of tile sums (1 block) ----------------
__global__ __launch_bounds__(128) void scanB_kernel(unsigned* __restrict__ psum, int nb) {
    __shared__ unsigned s[128];
    const int t = threadIdx.x;
    const unsigned v = (t < nb) ? psum[t] : 0u;
    s[t] = v;
    for (int off = 1; off < 128; off <<= 1) {
        __syncthreads();
        const unsigned x = (t >= off) ? s[t - off] : 0u;
        __syncthreads();
        s[t] += x;
    }
    __syncthreads();
    if (t < nb) psum[t] = s[t] - v;
}

// ---------------- Scan step C: add tile offsets, init cursor ----------------
__global__ __launch_bounds__(1024) void scanC_kernel(unsigned* __restrict__ base,
                                                     unsigned* __restrict__ cursor,
                                                     const unsigned* __restrict__ psum,
                                                     int N, int E_) {
    const int i = blockIdx.x * 1024 + threadIdx.x;
    if (i < N) {
        const unsigned b = base[i] + psum[blockIdx.x];
        base[i] = b;
        cursor[i] = b;
    }
    if (i == 0) base[N] = (unsigned)E_;
}

// ---------------- Kernel C: x = h@W; yp = half(x * rsqrt(deg+1)), padded to 32 ----------------
__global__ __launch_bounds__(256) void gemm_kernel(const float* __restrict__ h,
                                                   const float* __restrict__ W,
                                                   const unsigned long long* __restrict__ cd,
                                                   float* __restrict__ dis,
                                                   uint4* __restrict__ yp4, int N) {
    __shared__ float hs[256 * D];
    __shared__ float Ws[D * D];
    const int t = threadIdx.x;
    const int nb = blockIdx.x * 256;
    const int cnt = min(256, N - nb);
    const int total = cnt * D;

    for (int i = t; i < D * D; i += 256) Ws[i] = W[i];
    for (int i = t; i < total; i += 256) hs[i] = h[nb * D + i];
    __syncthreads();

    float x[D];
    float dv = 0.f;
    if (t < cnt) {
        const int n = nb + t;
#pragma unroll
        for (int j = 0; j < D; ++j) x[j] = 0.f;
#pragma unroll
        for (int k = 0; k < D; ++k) {
            const float hv = hs[t * D + k];
#pragma unroll
            for (int j = 0; j < D; ++j) x[j] += hv * Ws[k * D + j];
        }
        const float deg = (float)(unsigned)(cd[n] & 0xffffffffull) * (1.0f / FIXS);
        dv = rsqrtf(deg + 1.0f);  // +1 = self-loop weight
        dis[n] = dv;
    }
    __syncthreads();             // everyone done reading hs
    __half* hsh = (__half*)hs;   // reuse LDS as half[256][32]
    if (t < cnt) {
#pragma unroll
        for (int j = 0; j < D; ++j) hsh[t * 32 + j] = __float2half_rn(x[j] * dv);
        hsh[t * 32 + 30] = __float2half_rn(0.f);
        hsh[t * 32 + 31] = __float2half_rn(0.f);
    }
    __syncthreads();
    const uint4* hv4 = (const uint4*)hs;
    for (int i = t; i < cnt * 4; i += 256) yp4[nb * 4 + i] = hv4[i];
}

// ---------------- Kernel D: sort edges by destination node (native u32 cursor) ----------------
__global__ __launch_bounds__(256) void binscatter_kernel(const int* __restrict__ row,
                                                         const int* __restrict__ col,
                                                         const float* __restrict__ ew,
                                                         unsigned* __restrict__ cursor,
                                                         uint2* __restrict__ keysw, int E) {
    const int stride = gridDim.x * 256;
    for (int e = blockIdx.x * 256 + threadIdx.x; e < E; e += stride) {
        const unsigned slot = atomicAdd(&cursor[col[e]], 1u);
        keysw[slot] = make_uint2((unsigned)row[e], __float_as_uint(ew[e]));
    }
}

// ---------------- Kernel E: register aggregation (4 lanes/node) + fused MLP ----------------
__global__ __launch_bounds__(512) void aggmlp_kernel(const uint4* __restrict__ yp4,
                                                     const float* __restrict__ dis,
                                                     const unsigned* __restrict__ base,
                                                     const uint2* __restrict__ keysw,
                                                     const float* __restrict__ convb,
                                                     const float* __restrict__ w1,
                                                     const float* __restrict__ b1,
                                                     const float* __restrict__ w2,
                                                     const float* __restrict__ b2,
                                                     const float* __restrict__ w3,
                                                     const float* __restrict__ b3,
                                                     const float* __restrict__ w4,
                                                     const float* __restrict__ b4,
                                                     float* __restrict__ out, int N) {
    __shared__ float fs[128 * 33];   // pad-33: bank = (t + j) mod 32, conflict-free MLP reads
    __shared__ float cb[D];
    __shared__ float W1[300], B1[10], W2[100], B2[10], W3[100], B3[10], W4[10], B4v[1];
    const int t = threadIdx.x;
    if (t < D) cb[t] = convb[t];
    for (int i = t; i < 300; i += 512) W1[i] = w1[i];
    if (t < 100) W2[t] = w2[t];
    if (t >= 128 && t < 228) W3[t - 128] = w3[t - 128];
    if (t < 10) { B1[t] = b1[t]; B2[t] = b2[t]; B3[t] = b3[t]; W4[t] = w4[t]; }
    if (t == 0) B4v[0] = b4[0];

    const int nb = blockIdx.x * 128;
    const int local = t >> 2;
    const int q = t & 3;               // feature quad: elements q*8 .. q*8+7
    const int n = nb + local;
    const bool active = n < N;

    float acc[8];
    unsigned e = 0, e1 = 0;
    if (active) {
        const uint4 v = yp4[(size_t)n * 4 + q];   // self-loop init (ew = 1)
        const __half2* hh = (const __half2*)&v;
        float2 f;
        f = __half22float2(hh[0]); acc[0] = f.x; acc[1] = f.y;
        f = __half22float2(hh[1]); acc[2] = f.x; acc[3] = f.y;
        f = __half22float2(hh[2]); acc[4] = f.x; acc[5] = f.y;
        f = __half22float2(hh[3]); acc[6] = f.x; acc[7] = f.y;
        e = base[n];
        e1 = base[n + 1];
    } else {
#pragma unroll
        for (int j = 0; j < 8; ++j) acc[j] = 0.f;
    }

#define EDGE(EI)                                                                     \
    {                                                                                \
        const uint2 kw = keysw[EI];                                                  \
        const float w = __uint_as_float(kw.y);                                       \
        const uint4 v = yp4[(size_t)kw.x * 4 + q];                                   \
        const __half2* hh = (const __half2*)&v;                                      \
        const float2 f0 = __half22float2(hh[0]);                                     \
        const float2 f1 = __half22float2(hh[1]);                                     \
        const float2 f2 = __half22float2(hh[2]);                                     \
        const float2 f3 = __half22float2(hh[3]);                                     \
        acc[0] += f0.x * w; acc[1] += f0.y * w;                                      \
        acc[2] += f1.x * w; acc[3] += f1.y * w;                                      \
        acc[4] += f2.x * w; acc[5] += f2.y * w;                                      \
        acc[6] += f3.x * w; acc[7] += f3.y * w;                                      \
    }

    while (e + 2 <= e1) { EDGE(e) EDGE(e + 1) e += 2; }
    if (e < e1) EDGE(e)

    if (active) {
        const int bo = local * 33 + q * 8;
#pragma unroll
        for (int j = 0; j < 8; ++j) fs[bo + j] = acc[j];
    }
    __syncthreads();

    if (t < 128 && nb + t < N) {
        const int nn = nb + t;
        const float dv = dis[nn];
        const int bo = t * 33;
        float v[D];
#pragma unroll
        for (int j = 0; j < D; ++j) v[j] = fmaxf(dv * fs[bo + j] + cb[j], 0.f);
        float h1[10];
#pragma unroll
        for (int j = 0; j < 10; ++j) h1[j] = B1[j];
#pragma unroll
        for (int k = 0; k < D; ++k) {
            const float vv = v[k];
#pragma unroll
            for (int j = 0; j < 10; ++j) h1[j] += vv * W1[k * 10 + j];
        }
#pragma unroll
        for (int j = 0; j < 10; ++j) h1[j] = fmaxf(h1[j], 0.f);
        float h2[10];
#pragma unroll
        for (int j = 0; j < 10; ++j) h2[j] = B2[j];
#pragma unroll
        for (int k = 0; k < 10; ++k) {
            const float vv = h1[k];
#pragma unroll
            for (int j = 0; j < 10; ++j) h2[j] += vv * W2[k * 10 + j];
        }
#pragma unroll
        for (int j = 0; j < 10; ++j) h2[j] = fmaxf(h2[j], 0.f);
        float h3[10];
#pragma unroll
        for (int j = 0; j < 10; ++j) h3[j] = B3[j];
#pragma unroll
        for (int k = 0; k < 10; ++k) {
            const float vv = h2[k];
#pragma unroll
            for (int j = 0; j < 10; ++j) h3[j] += vv * W3[k * 10 + j];
        }
#pragma unroll
        for (int j = 0; j < 10; ++j) h3[j] = fmaxf(h3[j], 0.f);
        float z = B4v[0];
#pragma unroll
        for (int k = 0; k < 10; ++k) z += h3[k] * W4[k];
        out[nn] = 1.f / (1.f + expf(-z));
    }
}

extern "C" void kernel_launch(void* const* d_in, const int* in_sizes, int n_in,
                              void* d_out, int out_size, void* d_ws, size_t ws_size,
                              hipStream_t stream) {
    const float* h   = (const float*)d_in[0];
    const int*   ei  = (const int*)d_in[1];   // [2, E]: row = ei[0:E], col = ei[E:2E]
    const float* ew  = (const float*)d_in[2];
    const float* convW = (const float*)d_in[3];
    const float* convb = (const float*)d_in[4];
    const float* w1 = (const float*)d_in[5];
    const float* b1 = (const float*)d_in[6];
    const float* w2 = (const float*)d_in[7];
    const float* b2 = (const float*)d_in[8];
    const float* w3 = (const float*)d_in[9];
    const float* b3 = (const float*)d_in[10];
    const float* w4 = (const float*)d_in[11];
    const float* b4 = (const float*)d_in[12];
    float* out = (float*)d_out;

    const int N = in_sizes[0] / D;
    const int E = in_sizes[2];
    const int* row = ei;
    const int* col = ei + E;

    const int ntiles = (N + 1023) / 1024;       // 98 for N=100000 (must be <= 128)
    const int nblk256 = (N + 255) / 256;        // gemm blocks
    const int nblk128 = (N + 127) / 128;        // aggmlp blocks

    // workspace: yp[N*32 half] | keysw[E uint2] | cd[N u64] | dis[N] | base[N+1] | cursor[N] | psum[128]
    __half* yp = (__half*)d_ws;
    uint2* keysw = (uint2*)(yp + (size_t)N * 32);
    unsigned long long* cd = (unsigned long long*)(keysw + E);
    float* dis = (float*)(cd + N);
    unsigned* base   = (unsigned*)(dis + N);
    unsigned* cursor = base + (N + 1);
    unsigned* psum   = cursor + N;

    hipMemsetAsync(cd, 0, (size_t)N * sizeof(unsigned long long), stream);

    hist_kernel<<<1024, 256, 0, stream>>>(col, ew, cd, E);
    scanA_kernel<<<ntiles, 1024, 0, stream>>>(cd, base, psum, N);
    scanB_kernel<<<1, 128, 0, stream>>>(psum, ntiles);
    scanC_kernel<<<ntiles, 1024, 0, stream>>>(base, cursor, psum, N, E);
    gemm_kernel<<<nblk256, 256, 0, stream>>>(h, convW, cd, dis, (uint4*)yp, N);
    binscatter_kernel<<<2048, 256, 0, stream>>>(row, col, ew, cursor, keysw, E);
    aggmlp_kernel<<<nblk128, 512, 0, stream>>>((const uint4*)yp, dis, base, keysw, convb,
                                               w1, b1, w2, b2, w3, b3, w4, b4, out, N);
}

// Round 5
// 301.744 us; speedup vs baseline: 2.9657x; 1.6736x over previous
//
#include <hip/hip_runtime.h>
#include <hip/hip_fp16.h>
#include <math.h>

#define D 30
#define FIXS 16777216.0f     // 2^24 fixed-point scale for degree weights
#define FIXA 1048576.0f      // 2^20 fixed-point scale for feature aggregation
#define BKT 64               // destination nodes per bucket
#define LGB 6
#define CHUNK 8192           // edges per binning block
#define ROWBITS 18
#define ROWMASK ((1u << ROWBITS) - 1)
#define MAXBKT 2048

// ---------------- Kernel A: per-node u64 count|fixdeg + per-bucket histogram ----------------
__global__ __launch_bounds__(256) void hist_kernel(const int* __restrict__ col,
                                                   const float* __restrict__ ew,
                                                   unsigned long long* __restrict__ cd,
                                                   unsigned* __restrict__ bhist,
                                                   int E, int nbkt) {
    __shared__ unsigned lh[MAXBKT];
    const int t = threadIdx.x;
    for (int i = t; i < nbkt; i += 256) lh[i] = 0;
    __syncthreads();
    const int stride = gridDim.x * 256;
    for (int e = blockIdx.x * 256 + t; e < E; e += stride) {
        const int c = col[e];
        const unsigned fix = (unsigned)(ew[e] * FIXS);
        atomicAdd(&cd[c], (1ull << 32) | (unsigned long long)fix);
        atomicAdd(&lh[c >> LGB], 1u);
    }
    __syncthreads();
    for (int i = t; i < nbkt; i += 256) {
        const unsigned v = lh[i];
        if (v) atomicAdd(&bhist[i], v);
    }
}

// ---------------- Kernel B: exclusive scan of bucket counts (multi-tile, 1 block) ----------------
__global__ __launch_bounds__(1024) void bscan_kernel(const unsigned* __restrict__ bhist,
                                                     unsigned* __restrict__ base,
                                                     unsigned* __restrict__ cursor,
                                                     int nbkt, int E_) {
    __shared__ unsigned s[1024];
    __shared__ unsigned carry_s;
    const int t = threadIdx.x;
    if (t == 0) carry_s = 0;
    const int ntiles = (nbkt + 1023) >> 10;
    for (int tile = 0; tile < ntiles; ++tile) {
        const int idx = (tile << 10) + t;
        const unsigned v = (idx < nbkt) ? bhist[idx] : 0u;
        __syncthreads();
        s[t] = v;
        for (int off = 1; off < 1024; off <<= 1) {
            __syncthreads();
            const unsigned x = (t >= off) ? s[t - off] : 0u;
            __syncthreads();
            s[t] += x;
        }
        __syncthreads();
        const unsigned carry = carry_s;
        const unsigned excl = carry + s[t] - v;
        if (idx < nbkt) { base[idx] = excl; cursor[idx] = excl; }
        __syncthreads();
        if (t == 1023) carry_s = carry + s[1023];
    }
    if (t == 0) base[nbkt] = (unsigned)E_;
}

// ---------------- Kernel C: x = h@W; yp = half(x * rsqrt(deg+1)), padded to 32 ----------------
__global__ __launch_bounds__(256) void gemm_kernel(const float* __restrict__ h,
                                                   const float* __restrict__ W,
                                                   const unsigned long long* __restrict__ cd,
                                                   float* __restrict__ dis,
                                                   uint4* __restrict__ yp4, int N) {
    __shared__ float hs[256 * D];
    __shared__ float Ws[D * D];
    const int t = threadIdx.x;
    const int nb = blockIdx.x * 256;
    const int cnt = min(256, N - nb);
    const int total = cnt * D;

    for (int i = t; i < D * D; i += 256) Ws[i] = W[i];
    for (int i = t; i < total; i += 256) hs[i] = h[nb * D + i];
    __syncthreads();

    float x[D];
    float dv = 0.f;
    if (t < cnt) {
        const int n = nb + t;
#pragma unroll
        for (int j = 0; j < D; ++j) x[j] = 0.f;
#pragma unroll
        for (int k = 0; k < D; ++k) {
            const float hv = hs[t * D + k];
#pragma unroll
            for (int j = 0; j < D; ++j) x[j] += hv * Ws[k * D + j];
        }
        const float deg = (float)(unsigned)(cd[n] & 0xffffffffull) * (1.0f / FIXS);
        dv = rsqrtf(deg + 1.0f);  // +1 = self-loop weight
        dis[n] = dv;
    }
    __syncthreads();
    __half* hsh = (__half*)hs;   // reuse LDS as half[256][32]
    if (t < cnt) {
#pragma unroll
        for (int j = 0; j < D; ++j) hsh[t * 32 + j] = __float2half_rn(x[j] * dv);
        hsh[t * 32 + 30] = __float2half_rn(0.f);
        hsh[t * 32 + 31] = __float2half_rn(0.f);
    }
    __syncthreads();
    const uint4* hv4 = (const uint4*)hs;
    for (int i = t; i < cnt * 4; i += 256) yp4[nb * 4 + i] = hv4[i];
}

// ---------------- Kernel D: bin edges by destination bucket (all-native atomics) ----------------
__global__ __launch_bounds__(256) void binscatter_kernel(const int* __restrict__ row,
                                                         const int* __restrict__ col,
                                                         const float* __restrict__ ew,
                                                         unsigned* __restrict__ cursor,
                                                         uint2* __restrict__ keysw,
                                                         int E, int nbkt) {
    __shared__ unsigned lh[MAXBKT];
    const int t = threadIdx.x;
    const int e0 = blockIdx.x * CHUNK;
    const int e1 = min(e0 + CHUNK, E);
    for (int i = t; i < nbkt; i += 256) lh[i] = 0;
    __syncthreads();
    for (int e = e0 + t; e < e1; e += 256) atomicAdd(&lh[col[e] >> LGB], 1u);
    __syncthreads();
    for (int i = t; i < nbkt; i += 256) {
        const unsigned c = lh[i];
        if (c) lh[i] = atomicAdd(&cursor[i], c);
    }
    __syncthreads();
    for (int e = e0 + t; e < e1; e += 256) {
        const int c = col[e];
        const int b = c >> LGB;
        const unsigned slot = atomicAdd(&lh[b], 1u);
        keysw[slot] = make_uint2(((unsigned)(c & (BKT - 1)) << ROWBITS) | (unsigned)row[e],
                                 __float_as_uint(ew[e]));
    }
}

// ---------------- Kernel E: bucket aggregation via native int LDS atomics + fused MLP ----------------
__global__ __launch_bounds__(256) void aggmlp_kernel(const uint4* __restrict__ yp4,
                                                     const float* __restrict__ dis,
                                                     const unsigned* __restrict__ base,
                                                     const uint2* __restrict__ keysw,
                                                     const float* __restrict__ convb,
                                                     const float* __restrict__ w1,
                                                     const float* __restrict__ b1,
                                                     const float* __restrict__ w2,
                                                     const float* __restrict__ b2,
                                                     const float* __restrict__ w3,
                                                     const float* __restrict__ b3,
                                                     const float* __restrict__ w4,
                                                     const float* __restrict__ b4,
                                                     float* __restrict__ out, int N) {
    __shared__ int acci[BKT * 32];   // fixed-point accumulator, XOR-swizzled
    __shared__ float cb[D];
    __shared__ float W1[300], B1[10], W2[100], B2[10], W3[100], B3[10], W4[10], B4v[1];
    const int t = threadIdx.x;
    if (t < D) cb[t] = convb[t];
    for (int i = t; i < 300; i += 256) W1[i] = w1[i];
    if (t < 100) W2[t] = w2[t];
    if (t >= 128 && t < 228) W3[t - 128] = w3[t - 128];
    if (t < 10) { B1[t] = b1[t]; B2[t] = b2[t]; B3[t] = b3[t]; W4[t] = w4[t]; }
    if (t == 0) B4v[0] = b4[0];

    const int b = blockIdx.x;
    const int nb = b * BKT;
    const int cnt = min(BKT, N - nb);

    // self-loop init: acc = fix(y_self)   (swizzled, no atomics needed)
    for (int i = t; i < cnt * 4; i += 256) {
        const int n = i >> 2, q = i & 3;
        const uint4 v = yp4[(size_t)(nb + n) * 4 + q];
        const __half2* hh = (const __half2*)&v;
        const float2 f0 = __half22float2(hh[0]);
        const float2 f1 = __half22float2(hh[1]);
        const float2 f2 = __half22float2(hh[2]);
        const float2 f3 = __half22float2(hh[3]);
        const int bo = n << 5, sw = (n & 7) << 2, wb = q << 3;
        acci[bo + ((wb + 0) ^ sw)] = __float2int_rn(f0.x * FIXA);
        acci[bo + ((wb + 1) ^ sw)] = __float2int_rn(f0.y * FIXA);
        acci[bo + ((wb + 2) ^ sw)] = __float2int_rn(f1.x * FIXA);
        acci[bo + ((wb + 3) ^ sw)] = __float2int_rn(f1.y * FIXA);
        acci[bo + ((wb + 4) ^ sw)] = __float2int_rn(f2.x * FIXA);
        acci[bo + ((wb + 5) ^ sw)] = __float2int_rn(f2.y * FIXA);
        acci[bo + ((wb + 6) ^ sw)] = __float2int_rn(f3.x * FIXA);
        acci[bo + ((wb + 7) ^ sw)] = __float2int_rn(f3.y * FIXA);
    }
    __syncthreads();

    const unsigned e0v = base[b], e1v = base[b + 1];
    const int m = (int)(e1v - e0v) * 4;   // 4 lanes per edge

#define EDGE(kw, q)                                                                  \
    {                                                                                \
        const float wf = __uint_as_float((kw).y) * FIXA;                             \
        const uint4 v = yp4[(size_t)((kw).x & ROWMASK) * 4 + (q)];                   \
        const __half2* hh = (const __half2*)&v;                                      \
        const float2 f0 = __half22float2(hh[0]);                                     \
        const float2 f1 = __half22float2(hh[1]);                                     \
        const float2 f2 = __half22float2(hh[2]);                                     \
        const float2 f3 = __half22float2(hh[3]);                                     \
        const int loc = (int)((kw).x >> ROWBITS);                                    \
        const int bo = loc << 5;                                                     \
        const int sw = (loc & 7) << 2;                                               \
        const int wb = (q) << 3;                                                     \
        atomicAdd(&acci[bo + ((wb + 0) ^ sw)], __float2int_rn(f0.x * wf));           \
        atomicAdd(&acci[bo + ((wb + 1) ^ sw)], __float2int_rn(f0.y * wf));           \
        atomicAdd(&acci[bo + ((wb + 2) ^ sw)], __float2int_rn(f1.x * wf));           \
        atomicAdd(&acci[bo + ((wb + 3) ^ sw)], __float2int_rn(f1.y * wf));           \
        atomicAdd(&acci[bo + ((wb + 4) ^ sw)], __float2int_rn(f2.x * wf));           \
        atomicAdd(&acci[bo + ((wb + 5) ^ sw)], __float2int_rn(f2.y * wf));           \
        atomicAdd(&acci[bo + ((wb + 6) ^ sw)], __float2int_rn(f3.x * wf));           \
        atomicAdd(&acci[bo + ((wb + 7) ^ sw)], __float2int_rn(f3.y * wf));           \
    }

    for (int i = t; i < m; i += 512) {
        const int iB = i + 256;
        const uint2 kwA = keysw[e0v + (unsigned)(i >> 2)];
        const int qA = i & 3;
        if (iB < m) {
            const uint2 kwB = keysw[e0v + (unsigned)(iB >> 2)];
            const int qB = iB & 3;
            EDGE(kwA, qA)
            EDGE(kwB, qB)
        } else {
            EDGE(kwA, qA)
        }
    }
    __syncthreads();

    if (t < cnt) {
        const int nn = nb + t;
        const float dv = dis[nn] * (1.0f / FIXA);   // fold fixed-point descale into dis
        const int bo = t << 5;
        const int sw = (t & 7) << 2;
        float v[D];
#pragma unroll
        for (int j = 0; j < D; ++j)
            v[j] = fmaxf(dv * (float)acci[bo + (j ^ sw)] + cb[j], 0.f);
        float h1[10];
#pragma unroll
        for (int j = 0; j < 10; ++j) h1[j] = B1[j];
#pragma unroll
        for (int k = 0; k < D; ++k) {
            const float vv = v[k];
#pragma unroll
            for (int j = 0; j < 10; ++j) h1[j] += vv * W1[k * 10 + j];
        }
#pragma unroll
        for (int j = 0; j < 10; ++j) h1[j] = fmaxf(h1[j], 0.f);
        float h2[10];
#pragma unroll
        for (int j = 0; j < 10; ++j) h2[j] = B2[j];
#pragma unroll
        for (int k = 0; k < 10; ++k) {
            const float vv = h1[k];
#pragma unroll
            for (int j = 0; j < 10; ++j) h2[j] += vv * W2[k * 10 + j];
        }
#pragma unroll
        for (int j = 0; j < 10; ++j) h2[j] = fmaxf(h2[j], 0.f);
        float h3[10];
#pragma unroll
        for (int j = 0; j < 10; ++j) h3[j] = B3[j];
#pragma unroll
        for (int k = 0; k < 10; ++k) {
            const float vv = h2[k];
#pragma unroll
            for (int j = 0; j < 10; ++j) h3[j] += vv * W3[k * 10 + j];
        }
#pragma unroll
        for (int j = 0; j < 10; ++j) h3[j] = fmaxf(h3[j], 0.f);
        float z = B4v[0];
#pragma unroll
        for (int k = 0; k < 10; ++k) z += h3[k] * W4[k];
        out[nn] = 1.f / (1.f + expf(-z));
    }
}

extern "C" void kernel_launch(void* const* d_in, const int* in_sizes, int n_in,
                              void* d_out, int out_size, void* d_ws, size_t ws_size,
                              hipStream_t stream) {
    const float* h   = (const float*)d_in[0];
    const int*   ei  = (const int*)d_in[1];   // [2, E]: row = ei[0:E], col = ei[E:2E]
    const float* ew  = (const float*)d_in[2];
    const float* convW = (const float*)d_in[3];
    const float* convb = (const float*)d_in[4];
    const float* w1 = (const float*)d_in[5];
    const float* b1 = (const float*)d_in[6];
    const float* w2 = (const float*)d_in[7];
    const float* b2 = (const float*)d_in[8];
    const float* w3 = (const float*)d_in[9];
    const float* b3 = (const float*)d_in[10];
    const float* w4 = (const float*)d_in[11];
    const float* b4 = (const float*)d_in[12];
    float* out = (float*)d_out;

    const int N = in_sizes[0] / D;
    const int E = in_sizes[2];
    const int* row = ei;
    const int* col = ei + E;

    const int nbkt = (N + BKT - 1) >> LGB;       // 1563 for N=100000
    const int nchunks = (E + CHUNK - 1) / CHUNK; // 391
    const int nblk256 = (N + 255) / 256;         // gemm blocks

    // workspace: yp[N*32 half] | keysw[E uint2] | cd[N u64] | dis[N] | bhist | base | cursor
    __half* yp = (__half*)d_ws;
    uint2* keysw = (uint2*)(yp + (size_t)N * 32);
    unsigned long long* cd = (unsigned long long*)(keysw + E);
    float* dis = (float*)(cd + N);
    unsigned* bhist  = (unsigned*)(dis + N);
    unsigned* base   = bhist + nbkt;
    unsigned* cursor = base + (nbkt + 1);

    hipMemsetAsync(cd, 0, (size_t)N * sizeof(unsigned long long), stream);
    hipMemsetAsync(bhist, 0, (size_t)nbkt * sizeof(unsigned), stream);

    hist_kernel<<<1024, 256, 0, stream>>>(col, ew, cd, bhist, E, nbkt);
    bscan_kernel<<<1, 1024, 0, stream>>>(bhist, base, cursor, nbkt, E);
    gemm_kernel<<<nblk256, 256, 0, stream>>>(h, convW, cd, dis, (uint4*)yp, N);
    binscatter_kernel<<<nchunks, 256, 0, stream>>>(row, col, ew, cursor, keysw, E, nbkt);
    aggmlp_kernel<<<nbkt, 256, 0, stream>>>((const uint4*)yp, dis, base, keysw, convb,
                                            w1, b1, w2, b2, w3, b3, w4, b4, out, N);
}

// Round 6
// 173.746 us; speedup vs baseline: 5.1506x; 1.7367x over previous
//
#include <hip/hip_runtime.h>
#include <hip/hip_fp16.h>
#include <math.h>

#define D 30
#define FIXS 16777216.0f     // 2^24 fixed-point scale for degree weights
#define FIXA 1048576.0f      // 2^20 fixed-point scale for feature aggregation
#define BKT 64               // destination nodes per bucket
#define LGB 6
#define CHUNK 8192           // edges per binning block
#define ROWBITS 18
#define ROWMASK ((1u << ROWBITS) - 1)
#define MAXBKT 2048

// ---------------- Kernel A: per-bucket edge histogram only (no per-node atomics) ----------------
__global__ __launch_bounds__(256) void hist_kernel(const int* __restrict__ col,
                                                   unsigned* __restrict__ bhist,
                                                   int E, int nbkt) {
    __shared__ unsigned lh[MAXBKT];
    const int t = threadIdx.x;
    for (int i = t; i < nbkt; i += 256) lh[i] = 0;
    __syncthreads();
    const int gid = blockIdx.x * 256 + t;
    const int stride = gridDim.x * 256;
    const int E4 = E >> 2;
    const int4* col4 = (const int4*)col;
    for (int i = gid; i < E4; i += stride) {
        const int4 c = col4[i];
        atomicAdd(&lh[c.x >> LGB], 1u);
        atomicAdd(&lh[c.y >> LGB], 1u);
        atomicAdd(&lh[c.z >> LGB], 1u);
        atomicAdd(&lh[c.w >> LGB], 1u);
    }
    for (int e = (E4 << 2) + gid; e < E; e += stride) atomicAdd(&lh[col[e] >> LGB], 1u);
    __syncthreads();
    for (int i = t; i < nbkt; i += 256) {
        const unsigned v = lh[i];
        if (v) atomicAdd(&bhist[i], v);
    }
}

// ---------------- Kernel B: exclusive scan of bucket counts (multi-tile, 1 block) ----------------
__global__ __launch_bounds__(1024) void bscan_kernel(const unsigned* __restrict__ bhist,
                                                     unsigned* __restrict__ base,
                                                     unsigned* __restrict__ cursor,
                                                     int nbkt, int E_) {
    __shared__ unsigned s[1024];
    __shared__ unsigned carry_s;
    const int t = threadIdx.x;
    if (t == 0) carry_s = 0;
    const int ntiles = (nbkt + 1023) >> 10;
    for (int tile = 0; tile < ntiles; ++tile) {
        const int idx = (tile << 10) + t;
        const unsigned v = (idx < nbkt) ? bhist[idx] : 0u;
        __syncthreads();
        s[t] = v;
        for (int off = 1; off < 1024; off <<= 1) {
            __syncthreads();
            const unsigned x = (t >= off) ? s[t - off] : 0u;
            __syncthreads();
            s[t] += x;
        }
        __syncthreads();
        const unsigned carry = carry_s;
        const unsigned excl = carry + s[t] - v;
        if (idx < nbkt) { base[idx] = excl; cursor[idx] = excl; }
        __syncthreads();
        if (t == 1023) carry_s = carry + s[1023];
    }
    if (t == 0) base[nbkt] = (unsigned)E_;
}

// ---------------- Kernel D: bin edges by destination bucket (all-native atomics) ----------------
__global__ __launch_bounds__(256) void binscatter_kernel(const int* __restrict__ row,
                                                         const int* __restrict__ col,
                                                         const float* __restrict__ ew,
                                                         unsigned* __restrict__ cursor,
                                                         uint2* __restrict__ keysw,
                                                         int E, int nbkt) {
    __shared__ unsigned lh[MAXBKT];
    const int t = threadIdx.x;
    const int e0 = blockIdx.x * CHUNK;
    const int e1 = min(e0 + CHUNK, E);
    for (int i = t; i < nbkt; i += 256) lh[i] = 0;
    __syncthreads();
    for (int e = e0 + t; e < e1; e += 256) atomicAdd(&lh[col[e] >> LGB], 1u);
    __syncthreads();
    for (int i = t; i < nbkt; i += 256) {
        const unsigned c = lh[i];
        if (c) lh[i] = atomicAdd(&cursor[i], c);
    }
    __syncthreads();
    for (int e = e0 + t; e < e1; e += 256) {
        const int c = col[e];
        const int b = c >> LGB;
        const unsigned slot = atomicAdd(&lh[b], 1u);
        keysw[slot] = make_uint2(((unsigned)(c & (BKT - 1)) << ROWBITS) | (unsigned)row[e],
                                 __float_as_uint(ew[e]));
    }
}

// ---------------- Kernel D2: per-bucket degree from binned edges -> dis ----------------
__global__ __launch_bounds__(256) void degdis_kernel(const unsigned* __restrict__ base,
                                                     const uint2* __restrict__ keysw,
                                                     float* __restrict__ dis, int N) {
    __shared__ unsigned degf[BKT];
    const int t = threadIdx.x;
    if (t < BKT) degf[t] = 0;
    __syncthreads();
    const int b = blockIdx.x;
    const unsigned e0 = base[b], e1 = base[b + 1];
    for (unsigned e = e0 + t; e < e1; e += 256) {
        const uint2 kw = keysw[e];
        atomicAdd(&degf[kw.x >> ROWBITS], (unsigned)(__uint_as_float(kw.y) * FIXS));
    }
    __syncthreads();
    const int n = b * BKT + t;
    if (t < BKT && n < N)
        dis[n] = rsqrtf((float)degf[t] * (1.0f / FIXS) + 1.0f);  // +1 = self-loop
}

// ---------------- Kernel C: x = h@W; yp = half(x * dis), padded to 32 ----------------
__global__ __launch_bounds__(256) void gemm_kernel(const float* __restrict__ h,
                                                   const float* __restrict__ W,
                                                   const float* __restrict__ dis,
                                                   uint4* __restrict__ yp4, int N) {
    __shared__ float hs[256 * D];
    __shared__ float Ws[D * D];
    const int t = threadIdx.x;
    const int nb = blockIdx.x * 256;
    const int cnt = min(256, N - nb);
    const int total = cnt * D;

    for (int i = t; i < D * D; i += 256) Ws[i] = W[i];
    for (int i = t; i < total; i += 256) hs[i] = h[nb * D + i];
    __syncthreads();

    float x[D];
    float dv = 0.f;
    if (t < cnt) {
#pragma unroll
        for (int j = 0; j < D; ++j) x[j] = 0.f;
#pragma unroll
        for (int k = 0; k < D; ++k) {
            const float hv = hs[t * D + k];
#pragma unroll
            for (int j = 0; j < D; ++j) x[j] += hv * Ws[k * D + j];
        }
        dv = dis[nb + t];
    }
    __syncthreads();
    __half* hsh = (__half*)hs;   // reuse LDS as half[256][32]
    if (t < cnt) {
#pragma unroll
        for (int j = 0; j < D; ++j) hsh[t * 32 + j] = __float2half_rn(x[j] * dv);
        hsh[t * 32 + 30] = __float2half_rn(0.f);
        hsh[t * 32 + 31] = __float2half_rn(0.f);
    }
    __syncthreads();
    const uint4* hv4 = (const uint4*)hs;
    for (int i = t; i < cnt * 4; i += 256) yp4[nb * 4 + i] = hv4[i];
}

// ---------------- Kernel E: bucket aggregation via native int LDS atomics + fused MLP ----------------
__global__ __launch_bounds__(256) void aggmlp_kernel(const uint4* __restrict__ yp4,
                                                     const float* __restrict__ dis,
                                                     const unsigned* __restrict__ base,
                                                     const uint2* __restrict__ keysw,
                                                     const float* __restrict__ convb,
                                                     const float* __restrict__ w1,
                                                     const float* __restrict__ b1,
                                                     const float* __restrict__ w2,
                                                     const float* __restrict__ b2,
                                                     const float* __restrict__ w3,
                                                     const float* __restrict__ b3,
                                                     const float* __restrict__ w4,
                                                     const float* __restrict__ b4,
                                                     float* __restrict__ out, int N) {
    __shared__ int acci[BKT * 32];   // fixed-point accumulator, XOR-swizzled
    __shared__ float cb[D];
    __shared__ float W1[300], B1[10], W2[100], B2[10], W3[100], B3[10], W4[10], B4v[1];
    const int t = threadIdx.x;
    if (t < D) cb[t] = convb[t];
    for (int i = t; i < 300; i += 256) W1[i] = w1[i];
    if (t < 100) W2[t] = w2[t];
    if (t >= 128 && t < 228) W3[t - 128] = w3[t - 128];
    if (t < 10) { B1[t] = b1[t]; B2[t] = b2[t]; B3[t] = b3[t]; W4[t] = w4[t]; }
    if (t == 0) B4v[0] = b4[0];

    const int b = blockIdx.x;
    const int nb = b * BKT;
    const int cnt = min(BKT, N - nb);

    // self-loop init: acc = fix(y_self)   (swizzled, no atomics needed)
    for (int i = t; i < cnt * 4; i += 256) {
        const int n = i >> 2, q = i & 3;
        const uint4 v = yp4[(size_t)(nb + n) * 4 + q];
        const __half2* hh = (const __half2*)&v;
        const float2 f0 = __half22float2(hh[0]);
        const float2 f1 = __half22float2(hh[1]);
        const float2 f2 = __half22float2(hh[2]);
        const float2 f3 = __half22float2(hh[3]);
        const int bo = n << 5, sw = (n & 7) << 2, wb = q << 3;
        acci[bo + ((wb + 0) ^ sw)] = __float2int_rn(f0.x * FIXA);
        acci[bo + ((wb + 1) ^ sw)] = __float2int_rn(f0.y * FIXA);
        acci[bo + ((wb + 2) ^ sw)] = __float2int_rn(f1.x * FIXA);
        acci[bo + ((wb + 3) ^ sw)] = __float2int_rn(f1.y * FIXA);
        acci[bo + ((wb + 4) ^ sw)] = __float2int_rn(f2.x * FIXA);
        acci[bo + ((wb + 5) ^ sw)] = __float2int_rn(f2.y * FIXA);
        acci[bo + ((wb + 6) ^ sw)] = __float2int_rn(f3.x * FIXA);
        acci[bo + ((wb + 7) ^ sw)] = __float2int_rn(f3.y * FIXA);
    }
    __syncthreads();

    const unsigned e0v = base[b], e1v = base[b + 1];
    const int m = (int)(e1v - e0v) * 4;   // 4 lanes per edge

#define EDGE(kw, q)                                                                  \
    {                                                                                \
        const float wf = __uint_as_float((kw).y) * FIXA;                             \
        const uint4 v = yp4[(size_t)((kw).x & ROWMASK) * 4 + (q)];                   \
        const __half2* hh = (const __half2*)&v;                                      \
        const float2 f0 = __half22float2(hh[0]);                                     \
        const float2 f1 = __half22float2(hh[1]);                                     \
        const float2 f2 = __half22float2(hh[2]);                                     \
        const float2 f3 = __half22float2(hh[3]);                                     \
        const int loc = (int)((kw).x >> ROWBITS);                                    \
        const int bo = loc << 5;                                                     \
        const int sw = (loc & 7) << 2;                                               \
        const int wb = (q) << 3;                                                     \
        atomicAdd(&acci[bo + ((wb + 0) ^ sw)], __float2int_rn(f0.x * wf));           \
        atomicAdd(&acci[bo + ((wb + 1) ^ sw)], __float2int_rn(f0.y * wf));           \
        atomicAdd(&acci[bo + ((wb + 2) ^ sw)], __float2int_rn(f1.x * wf));           \
        atomicAdd(&acci[bo + ((wb + 3) ^ sw)], __float2int_rn(f1.y * wf));           \
        atomicAdd(&acci[bo + ((wb + 4) ^ sw)], __float2int_rn(f2.x * wf));           \
        atomicAdd(&acci[bo + ((wb + 5) ^ sw)], __float2int_rn(f2.y * wf));           \
        atomicAdd(&acci[bo + ((wb + 6) ^ sw)], __float2int_rn(f3.x * wf));           \
        atomicAdd(&acci[bo + ((wb + 7) ^ sw)], __float2int_rn(f3.y * wf));           \
    }

    for (int i = t; i < m; i += 512) {
        const int iB = i + 256;
        const uint2 kwA = keysw[e0v + (unsigned)(i >> 2)];
        const int qA = i & 3;
        if (iB < m) {
            const uint2 kwB = keysw[e0v + (unsigned)(iB >> 2)];
            const int qB = iB & 3;
            EDGE(kwA, qA)
            EDGE(kwB, qB)
        } else {
            EDGE(kwA, qA)
        }
    }
    __syncthreads();

    if (t < cnt) {
        const int nn = nb + t;
        const float dv = dis[nn] * (1.0f / FIXA);   // fold fixed-point descale into dis
        const int bo = t << 5;
        const int sw = (t & 7) << 2;
        float v[D];
#pragma unroll
        for (int j = 0; j < D; ++j)
            v[j] = fmaxf(dv * (float)acci[bo + (j ^ sw)] + cb[j], 0.f);
        float h1[10];
#pragma unroll
        for (int j = 0; j < 10; ++j) h1[j] = B1[j];
#pragma unroll
        for (int k = 0; k < D; ++k) {
            const float vv = v[k];
#pragma unroll
            for (int j = 0; j < 10; ++j) h1[j] += vv * W1[k * 10 + j];
        }
#pragma unroll
        for (int j = 0; j < 10; ++j) h1[j] = fmaxf(h1[j], 0.f);
        float h2[10];
#pragma unroll
        for (int j = 0; j < 10; ++j) h2[j] = B2[j];
#pragma unroll
        for (int k = 0; k < 10; ++k) {
            const float vv = h1[k];
#pragma unroll
            for (int j = 0; j < 10; ++j) h2[j] += vv * W2[k * 10 + j];
        }
#pragma unroll
        for (int j = 0; j < 10; ++j) h2[j] = fmaxf(h2[j], 0.f);
        float h3[10];
#pragma unroll
        for (int j = 0; j < 10; ++j) h3[j] = B3[j];
#pragma unroll
        for (int k = 0; k < 10; ++k) {
            const float vv = h2[k];
#pragma unroll
            for (int j = 0; j < 10; ++j) h3[j] += vv * W3[k * 10 + j];
        }
#pragma unroll
        for (int j = 0; j < 10; ++j) h3[j] = fmaxf(h3[j], 0.f);
        float z = B4v[0];
#pragma unroll
        for (int k = 0; k < 10; ++k) z += h3[k] * W4[k];
        out[nn] = 1.f / (1.f + expf(-z));
    }
}

extern "C" void kernel_launch(void* const* d_in, const int* in_sizes, int n_in,
                              void* d_out, int out_size, void* d_ws, size_t ws_size,
                              hipStream_t stream) {
    const float* h   = (const float*)d_in[0];
    const int*   ei  = (const int*)d_in[1];   // [2, E]: row = ei[0:E], col = ei[E:2E]
    const float* ew  = (const float*)d_in[2];
    const float* convW = (const float*)d_in[3];
    const float* convb = (const float*)d_in[4];
    const float* w1 = (const float*)d_in[5];
    const float* b1 = (const float*)d_in[6];
    const float* w2 = (const float*)d_in[7];
    const float* b2 = (const float*)d_in[8];
    const float* w3 = (const float*)d_in[9];
    const float* b3 = (const float*)d_in[10];
    const float* w4 = (const float*)d_in[11];
    const float* b4 = (const float*)d_in[12];
    float* out = (float*)d_out;

    const int N = in_sizes[0] / D;
    const int E = in_sizes[2];
    const int* row = ei;
    const int* col = ei + E;

    const int nbkt = (N + BKT - 1) >> LGB;       // 1563 for N=100000
    const int nchunks = (E + CHUNK - 1) / CHUNK; // 391
    const int nblk256 = (N + 255) / 256;         // gemm blocks

    // workspace: yp[N*32 half] | keysw[E uint2] | dis[N] | bhist | base | cursor
    __half* yp = (__half*)d_ws;
    uint2* keysw = (uint2*)(yp + (size_t)N * 32);
    float* dis = (float*)(keysw + E);
    unsigned* bhist  = (unsigned*)(dis + N);
    unsigned* base   = bhist + nbkt;
    unsigned* cursor = base + (nbkt + 1);

    hipMemsetAsync(bhist, 0, (size_t)nbkt * sizeof(unsigned), stream);

    hist_kernel<<<1024, 256, 0, stream>>>(col, bhist, E, nbkt);
    bscan_kernel<<<1, 1024, 0, stream>>>(bhist, base, cursor, nbkt, E);
    binscatter_kernel<<<nchunks, 256, 0, stream>>>(row, col, ew, cursor, keysw, E, nbkt);
    degdis_kernel<<<nbkt, 256, 0, stream>>>(base, keysw, dis, N);
    gemm_kernel<<<nblk256, 256, 0, stream>>>(h, convW, dis, (uint4*)yp, N);
    aggmlp_kernel<<<nbkt, 256, 0, stream>>>((const uint4*)yp, dis, base, keysw, convb,
                                            w1, b1, w2, b2, w3, b3, w4, b4, out, N);
}

// Round 7
// 149.479 us; speedup vs baseline: 5.9867x; 1.1623x over previous
//
#include <hip/hip_runtime.h>
#include <hip/hip_fp16.h>
#include <math.h>

#define D 30
#define FIXS 16777216.0f     // 2^24 fixed-point scale for degree weights
#define FIXA 1048576.0f      // 2^20 fixed-point scale for feature aggregation
#define BKT 64               // destination nodes per bucket
#define LGB 6
#define CHUNK 8192           // edges per chunk
#define ROWBITS 18
#define ROWMASK ((1u << ROWBITS) - 1)
#define MAXBKT 2048

// ---------------- Kernel 1: per-(chunk,bucket) counts ----------------
__global__ __launch_bounds__(1024) void count_kernel(const int* __restrict__ col,
                                                     unsigned* __restrict__ cnt,
                                                     int E, int nbkt) {
    __shared__ unsigned lh[MAXBKT];
    const int t = threadIdx.x;
    for (int i = t; i < nbkt; i += 1024) lh[i] = 0;
    __syncthreads();
    const int e0 = blockIdx.x * CHUNK;
    const int e1 = min(e0 + CHUNK, E);
    for (int e = e0 + t; e < e1; e += 1024) atomicAdd(&lh[col[e] >> LGB], 1u);
    __syncthreads();
    unsigned* dst = cnt + (size_t)blockIdx.x * nbkt;
    for (int i = t; i < nbkt; i += 1024) dst[i] = lh[i];
}

// ---------------- Scan A: tile-wise exclusive scan in bucket-major order ----------------
// scan index i = b*nchunks + c  <->  storage s = c*nbkt + b (bijective, blocks disjoint)
__global__ __launch_bounds__(1024) void scanA_kernel(unsigned* __restrict__ cnt,
                                                     unsigned* __restrict__ psum,
                                                     int nchunks, int nbkt, int M) {
    __shared__ unsigned s[1024];
    const int t = threadIdx.x;
    const int i = blockIdx.x * 1024 + t;
    unsigned v = 0;
    int sidx = 0;
    if (i < M) {
        const int b = i / nchunks;
        const int c = i - b * nchunks;
        sidx = c * nbkt + b;
        v = cnt[sidx];
    }
    s[t] = v;
    for (int off = 1; off < 1024; off <<= 1) {
        __syncthreads();
        const unsigned x = (t >= off) ? s[t - off] : 0u;
        __syncthreads();
        s[t] += x;
    }
    __syncthreads();
    if (i < M) cnt[sidx] = s[t] - v;          // exclusive within tile
    if (t == 1023) psum[blockIdx.x] = s[1023];
}

// ---------------- Scan B: exclusive scan of tile sums (1 block) ----------------
__global__ __launch_bounds__(1024) void scanB_kernel(unsigned* __restrict__ psum, int nt) {
    __shared__ unsigned s[1024];
    const int t = threadIdx.x;
    const unsigned v = (t < nt) ? psum[t] : 0u;
    s[t] = v;
    for (int off = 1; off < 1024; off <<= 1) {
        __syncthreads();
        const unsigned x = (t >= off) ? s[t - off] : 0u;
        __syncthreads();
        s[t] += x;
    }
    __syncthreads();
    if (t < nt) psum[t] = s[t] - v;
}

// ---------------- Scan C: add tile offsets; emit per-bucket base ----------------
__global__ __launch_bounds__(1024) void scanC_kernel(unsigned* __restrict__ cnt,
                                                     const unsigned* __restrict__ psum,
                                                     unsigned* __restrict__ base,
                                                     int nchunks, int nbkt, int M, int E_) {
    const int i = blockIdx.x * 1024 + threadIdx.x;
    if (i < M) {
        const int b = i / nchunks;
        const int c = i - b * nchunks;
        const unsigned val = cnt[c * nbkt + b] + psum[blockIdx.x];
        cnt[c * nbkt + b] = val;
        if (c == 0) base[b] = val;
    }
    if (i == 0) base[nbkt] = (unsigned)E_;
}

// ---------------- Kernel 2: scatter edges to sorted positions (no global atomics) ----------------
__global__ __launch_bounds__(1024) void scatter_kernel(const int* __restrict__ row,
                                                       const int* __restrict__ col,
                                                       const float* __restrict__ ew,
                                                       const unsigned* __restrict__ cnt,
                                                       uint2* __restrict__ keysw,
                                                       int E, int nbkt) {
    __shared__ unsigned lh[MAXBKT];
    const int t = threadIdx.x;
    const unsigned* src = cnt + (size_t)blockIdx.x * nbkt;
    for (int i = t; i < nbkt; i += 1024) lh[i] = src[i];
    __syncthreads();
    const int e0 = blockIdx.x * CHUNK;
    const int e1 = min(e0 + CHUNK, E);
    for (int e = e0 + t; e < e1; e += 1024) {
        const int c = col[e];
        const unsigned slot = atomicAdd(&lh[c >> LGB], 1u);
        keysw[slot] = make_uint2(((unsigned)(c & (BKT - 1)) << ROWBITS) | (unsigned)row[e],
                                 __float_as_uint(ew[e]));
    }
}

// ---------------- Kernel 3: per-bucket degree from binned edges -> dis ----------------
__global__ __launch_bounds__(256) void degdis_kernel(const unsigned* __restrict__ base,
                                                     const uint2* __restrict__ keysw,
                                                     float* __restrict__ dis, int N) {
    __shared__ unsigned degf[BKT];
    const int t = threadIdx.x;
    if (t < BKT) degf[t] = 0;
    __syncthreads();
    const int b = blockIdx.x;
    const unsigned e0 = base[b], e1 = base[b + 1];
    for (unsigned e = e0 + t; e < e1; e += 256) {
        const uint2 kw = keysw[e];
        atomicAdd(&degf[kw.x >> ROWBITS], (unsigned)(__uint_as_float(kw.y) * FIXS));
    }
    __syncthreads();
    const int n = b * BKT + t;
    if (t < BKT && n < N)
        dis[n] = rsqrtf((float)degf[t] * (1.0f / FIXS) + 1.0f);  // +1 = self-loop
}

// ---------------- Kernel 4: x = h@W; yp = half(x * dis), padded to 32 ----------------
__global__ __launch_bounds__(256) void gemm_kernel(const float* __restrict__ h,
                                                   const float* __restrict__ W,
                                                   const float* __restrict__ dis,
                                                   uint4* __restrict__ yp4, int N) {
    __shared__ float hs[256 * D];
    __shared__ float Ws[D * D];
    const int t = threadIdx.x;
    const int nb = blockIdx.x * 256;
    const int cnt = min(256, N - nb);
    const int total = cnt * D;

    for (int i = t; i < D * D; i += 256) Ws[i] = W[i];
    for (int i = t; i < total; i += 256) hs[i] = h[nb * D + i];
    __syncthreads();

    float x[D];
    float dv = 0.f;
    if (t < cnt) {
#pragma unroll
        for (int j = 0; j < D; ++j) x[j] = 0.f;
#pragma unroll
        for (int k = 0; k < D; ++k) {
            const float hv = hs[t * D + k];
#pragma unroll
            for (int j = 0; j < D; ++j) x[j] += hv * Ws[k * D + j];
        }
        dv = dis[nb + t];
    }
    __syncthreads();
    __half* hsh = (__half*)hs;   // reuse LDS as half[256][32]
    if (t < cnt) {
#pragma unroll
        for (int j = 0; j < D; ++j) hsh[t * 32 + j] = __float2half_rn(x[j] * dv);
        hsh[t * 32 + 30] = __float2half_rn(0.f);
        hsh[t * 32 + 31] = __float2half_rn(0.f);
    }
    __syncthreads();
    const uint4* hv4 = (const uint4*)hs;
    for (int i = t; i < cnt * 4; i += 256) yp4[nb * 4 + i] = hv4[i];
}

// ---------------- Kernel 5: bucket aggregation via native int LDS atomics + fused MLP ----------------
__global__ __launch_bounds__(512) void aggmlp_kernel(const uint4* __restrict__ yp4,
                                                     const float* __restrict__ dis,
                                                     const unsigned* __restrict__ base,
                                                     const uint2* __restrict__ keysw,
                                                     const float* __restrict__ convb,
                                                     const float* __restrict__ w1,
                                                     const float* __restrict__ b1,
                                                     const float* __restrict__ w2,
                                                     const float* __restrict__ b2,
                                                     const float* __restrict__ w3,
                                                     const float* __restrict__ b3,
                                                     const float* __restrict__ w4,
                                                     const float* __restrict__ b4,
                                                     float* __restrict__ out, int N) {
    __shared__ int acci[BKT * 32];   // fixed-point accumulator, XOR-swizzled
    __shared__ float cb[D];
    __shared__ float W1[300], B1[10], W2[100], B2[10], W3[100], B3[10], W4[10], B4v[1];
    const int t = threadIdx.x;
    if (t < D) cb[t] = convb[t];
    for (int i = t; i < 300; i += 512) W1[i] = w1[i];
    if (t < 100) W2[t] = w2[t];
    if (t >= 128 && t < 228) W3[t - 128] = w3[t - 128];
    if (t < 10) { B1[t] = b1[t]; B2[t] = b2[t]; B3[t] = b3[t]; W4[t] = w4[t]; }
    if (t == 0) B4v[0] = b4[0];

    const int b = blockIdx.x;
    const int nb = b * BKT;
    const int cnt = min(BKT, N - nb);

    // self-loop init: acc = fix(y_self)   (swizzled, no atomics needed)
    for (int i = t; i < cnt * 4; i += 512) {
        const int n = i >> 2, q = i & 3;
        const uint4 v = yp4[(size_t)(nb + n) * 4 + q];
        const __half2* hh = (const __half2*)&v;
        const float2 f0 = __half22float2(hh[0]);
        const float2 f1 = __half22float2(hh[1]);
        const float2 f2 = __half22float2(hh[2]);
        const float2 f3 = __half22float2(hh[3]);
        const int bo = n << 5, sw = (n & 7) << 2, wb = q << 3;
        acci[bo + ((wb + 0) ^ sw)] = __float2int_rn(f0.x * FIXA);
        acci[bo + ((wb + 1) ^ sw)] = __float2int_rn(f0.y * FIXA);
        acci[bo + ((wb + 2) ^ sw)] = __float2int_rn(f1.x * FIXA);
        acci[bo + ((wb + 3) ^ sw)] = __float2int_rn(f1.y * FIXA);
        acci[bo + ((wb + 4) ^ sw)] = __float2int_rn(f2.x * FIXA);
        acci[bo + ((wb + 5) ^ sw)] = __float2int_rn(f2.y * FIXA);
        acci[bo + ((wb + 6) ^ sw)] = __float2int_rn(f3.x * FIXA);
        acci[bo + ((wb + 7) ^ sw)] = __float2int_rn(f3.y * FIXA);
    }
    __syncthreads();

    const unsigned e0v = base[b], e1v = base[b + 1];
    const int m = (int)(e1v - e0v) * 4;   // 4 lanes per edge

#define EDGE(kw, q)                                                                  \
    {                                                                                \
        const float wf = __uint_as_float((kw).y) * FIXA;                             \
        const uint4 v = yp4[(size_t)((kw).x & ROWMASK) * 4 + (q)];                   \
        const __half2* hh = (const __half2*)&v;                                      \
        const float2 f0 = __half22float2(hh[0]);                                     \
        const float2 f1 = __half22float2(hh[1]);                                     \
        const float2 f2 = __half22float2(hh[2]);                                     \
        const float2 f3 = __half22float2(hh[3]);                                     \
        const int loc = (int)((kw).x >> ROWBITS);                                    \
        const int bo = loc << 5;                                                     \
        const int sw = (loc & 7) << 2;                                               \
        const int wb = (q) << 3;                                                     \
        atomicAdd(&acci[bo + ((wb + 0) ^ sw)], __float2int_rn(f0.x * wf));           \
        atomicAdd(&acci[bo + ((wb + 1) ^ sw)], __float2int_rn(f0.y * wf));           \
        atomicAdd(&acci[bo + ((wb + 2) ^ sw)], __float2int_rn(f1.x * wf));           \
        atomicAdd(&acci[bo + ((wb + 3) ^ sw)], __float2int_rn(f1.y * wf));           \
        atomicAdd(&acci[bo + ((wb + 4) ^ sw)], __float2int_rn(f2.x * wf));           \
        atomicAdd(&acci[bo + ((wb + 5) ^ sw)], __float2int_rn(f2.y * wf));           \
        atomicAdd(&acci[bo + ((wb + 6) ^ sw)], __float2int_rn(f3.x * wf));           \
        atomicAdd(&acci[bo + ((wb + 7) ^ sw)], __float2int_rn(f3.y * wf));           \
    }

    for (int i = t; i < m; i += 1024) {
        const int iB = i + 512;
        const uint2 kwA = keysw[e0v + (unsigned)(i >> 2)];
        const int qA = i & 3;
        if (iB < m) {
            const uint2 kwB = keysw[e0v + (unsigned)(iB >> 2)];
            const int qB = iB & 3;
            EDGE(kwA, qA)
            EDGE(kwB, qB)
        } else {
            EDGE(kwA, qA)
        }
    }
    __syncthreads();

    if (t < cnt) {
        const int nn = nb + t;
        const float dv = dis[nn] * (1.0f / FIXA);   // fold fixed-point descale into dis
        const int bo = t << 5;
        const int sw = (t & 7) << 2;
        float v[D];
#pragma unroll
        for (int j = 0; j < D; ++j)
            v[j] = fmaxf(dv * (float)acci[bo + (j ^ sw)] + cb[j], 0.f);
        float h1[10];
#pragma unroll
        for (int j = 0; j < 10; ++j) h1[j] = B1[j];
#pragma unroll
        for (int k = 0; k < D; ++k) {
            const float vv = v[k];
#pragma unroll
            for (int j = 0; j < 10; ++j) h1[j] += vv * W1[k * 10 + j];
        }
#pragma unroll
        for (int j = 0; j < 10; ++j) h1[j] = fmaxf(h1[j], 0.f);
        float h2[10];
#pragma unroll
        for (int j = 0; j < 10; ++j) h2[j] = B2[j];
#pragma unroll
        for (int k = 0; k < 10; ++k) {
            const float vv = h1[k];
#pragma unroll
            for (int j = 0; j < 10; ++j) h2[j] += vv * W2[k * 10 + j];
        }
#pragma unroll
        for (int j = 0; j < 10; ++j) h2[j] = fmaxf(h2[j], 0.f);
        float h3[10];
#pragma unroll
        for (int j = 0; j < 10; ++j) h3[j] = B3[j];
#pragma unroll
        for (int k = 0; k < 10; ++k) {
            const float vv = h2[k];
#pragma unroll
            for (int j = 0; j < 10; ++j) h3[j] += vv * W3[k * 10 + j];
        }
#pragma unroll
        for (int j = 0; j < 10; ++j) h3[j] = fmaxf(h3[j], 0.f);
        float z = B4v[0];
#pragma unroll
        for (int k = 0; k < 10; ++k) z += h3[k] * W4[k];
        out[nn] = 1.f / (1.f + expf(-z));
    }
}

extern "C" void kernel_launch(void* const* d_in, const int* in_sizes, int n_in,
                              void* d_out, int out_size, void* d_ws, size_t ws_size,
                              hipStream_t stream) {
    const float* h   = (const float*)d_in[0];
    const int*   ei  = (const int*)d_in[1];   // [2, E]: row = ei[0:E], col = ei[E:2E]
    const float* ew  = (const float*)d_in[2];
    const float* convW = (const float*)d_in[3];
    const float* convb = (const float*)d_in[4];
    const float* w1 = (const float*)d_in[5];
    const float* b1 = (const float*)d_in[6];
    const float* w2 = (const float*)d_in[7];
    const float* b2 = (const float*)d_in[8];
    const float* w3 = (const float*)d_in[9];
    const float* b3 = (const float*)d_in[10];
    const float* w4 = (const float*)d_in[11];
    const float* b4 = (const float*)d_in[12];
    float* out = (float*)d_out;

    const int N = in_sizes[0] / D;
    const int E = in_sizes[2];
    const int* row = ei;
    const int* col = ei + E;

    const int nbkt = (N + BKT - 1) >> LGB;        // 1563 for N=100000
    const int nchunks = (E + CHUNK - 1) / CHUNK;  // 391
    const int M = nchunks * nbkt;                 // 611133
    const int ntiles = (M + 1023) >> 10;          // 597 (must be <= 1024)
    const int nblk256 = (N + 255) / 256;          // gemm blocks

    // workspace: yp[N*32 half] | keysw[E uint2] | dis[N] | cnt[M] | base[nbkt+1] | psum[ntiles]
    __half* yp = (__half*)d_ws;
    uint2* keysw = (uint2*)(yp + (size_t)N * 32);
    float* dis = (float*)(keysw + E);
    unsigned* cntm = (unsigned*)(dis + N);
    unsigned* base = cntm + M;
    unsigned* psum = base + (nbkt + 1);

    count_kernel<<<nchunks, 1024, 0, stream>>>(col, cntm, E, nbkt);
    scanA_kernel<<<ntiles, 1024, 0, stream>>>(cntm, psum, nchunks, nbkt, M);
    scanB_kernel<<<1, 1024, 0, stream>>>(psum, ntiles);
    scanC_kernel<<<ntiles, 1024, 0, stream>>>(cntm, psum, base, nchunks, nbkt, M, E);
    scatter_kernel<<<nchunks, 1024, 0, stream>>>(row, col, ew, cntm, keysw, E, nbkt);
    degdis_kernel<<<nbkt, 256, 0, stream>>>(base, keysw, dis, N);
    gemm_kernel<<<nblk256, 256, 0, stream>>>(h, convW, dis, (uint4*)yp, N);
    aggmlp_kernel<<<nbkt, 512, 0, stream>>>((const uint4*)yp, dis, base, keysw, convb,
                                            w1, b1, w2, b2, w3, b3, w4, b4, out, N);
}

// Round 8
// 128.305 us; speedup vs baseline: 6.9747x; 1.1650x over previous
//
#include <hip/hip_runtime.h>
#include <hip/hip_fp16.h>
#include <math.h>

#define D 30
#define FIXS 16777216.0f     // 2^24 fixed-point scale for degree weights
#define FIXA 1048576.0f      // 2^20 fixed-point scale for feature aggregation
#define BKT 256              // destination nodes per bucket
#define LGB 8
#define CHUNK 8192           // edges per chunk
#define ROWBITS 18
#define ROWMASK ((1u << ROWBITS) - 1)
#define MAXBKT 512

// ---------------- Kernel 1: per-(chunk,bucket) counts ----------------
__global__ __launch_bounds__(1024) void count_kernel(const int* __restrict__ col,
                                                     unsigned* __restrict__ cnt,
                                                     int E, int nbkt) {
    __shared__ unsigned lh[MAXBKT];
    const int t = threadIdx.x;
    for (int i = t; i < nbkt; i += 1024) lh[i] = 0;
    __syncthreads();
    const int e0 = blockIdx.x * CHUNK;
    const int e1 = min(e0 + CHUNK, E);
    const int nv = (e1 - e0) >> 2;
    const int4* c4 = (const int4*)(col + e0);
    for (int i = t; i < nv; i += 1024) {
        const int4 c = c4[i];
        atomicAdd(&lh[c.x >> LGB], 1u);
        atomicAdd(&lh[c.y >> LGB], 1u);
        atomicAdd(&lh[c.z >> LGB], 1u);
        atomicAdd(&lh[c.w >> LGB], 1u);
    }
    for (int e = e0 + (nv << 2) + t; e < e1; e += 1024) atomicAdd(&lh[col[e] >> LGB], 1u);
    __syncthreads();
    unsigned* dst = cnt + (size_t)blockIdx.x * nbkt;
    for (int i = t; i < nbkt; i += 1024) dst[i] = lh[i];
}

// ---------------- Scan A: tile-wise exclusive scan in bucket-major order ----------------
// scan index i = b*nchunks + c  <->  storage s = c*nbkt + b (bijective, blocks disjoint)
__global__ __launch_bounds__(1024) void scanA_kernel(unsigned* __restrict__ cnt,
                                                     unsigned* __restrict__ psum,
                                                     int nchunks, int nbkt, int M) {
    __shared__ unsigned s[1024];
    const int t = threadIdx.x;
    const int i = blockIdx.x * 1024 + t;
    unsigned v = 0;
    int sidx = 0;
    if (i < M) {
        const int b = i / nchunks;
        const int c = i - b * nchunks;
        sidx = c * nbkt + b;
        v = cnt[sidx];
    }
    s[t] = v;
    for (int off = 1; off < 1024; off <<= 1) {
        __syncthreads();
        const unsigned x = (t >= off) ? s[t - off] : 0u;
        __syncthreads();
        s[t] += x;
    }
    __syncthreads();
    if (i < M) cnt[sidx] = s[t] - v;          // exclusive within tile
    if (t == 1023) psum[blockIdx.x] = s[1023];
}

// ---------------- Scan B: exclusive scan of tile sums (1 block) ----------------
__global__ __launch_bounds__(1024) void scanB_kernel(unsigned* __restrict__ psum, int nt) {
    __shared__ unsigned s[1024];
    const int t = threadIdx.x;
    const unsigned v = (t < nt) ? psum[t] : 0u;
    s[t] = v;
    for (int off = 1; off < 1024; off <<= 1) {
        __syncthreads();
        const unsigned x = (t >= off) ? s[t - off] : 0u;
        __syncthreads();
        s[t] += x;
    }
    __syncthreads();
    if (t < nt) psum[t] = s[t] - v;
}

// ---------------- Scan C: add tile offsets; emit per-bucket base ----------------
__global__ __launch_bounds__(1024) void scanC_kernel(unsigned* __restrict__ cnt,
                                                     const unsigned* __restrict__ psum,
                                                     unsigned* __restrict__ base,
                                                     int nchunks, int nbkt, int M, int E_) {
    const int i = blockIdx.x * 1024 + threadIdx.x;
    if (i < M) {
        const int b = i / nchunks;
        const int c = i - b * nchunks;
        const unsigned val = cnt[c * nbkt + b] + psum[blockIdx.x];
        cnt[c * nbkt + b] = val;
        if (c == 0) base[b] = val;
    }
    if (i == 0) base[nbkt] = (unsigned)E_;
}

// ---------------- Kernel 2: scatter edges to sorted positions (no global atomics) ----------------
__global__ __launch_bounds__(1024) void scatter_kernel(const int* __restrict__ row,
                                                       const int* __restrict__ col,
                                                       const float* __restrict__ ew,
                                                       const unsigned* __restrict__ cnt,
                                                       uint2* __restrict__ keysw,
                                                       int E, int nbkt) {
    __shared__ unsigned lh[MAXBKT];
    const int t = threadIdx.x;
    const unsigned* src = cnt + (size_t)blockIdx.x * nbkt;
    for (int i = t; i < nbkt; i += 1024) lh[i] = src[i];
    __syncthreads();
    const int e0 = blockIdx.x * CHUNK;
    const int e1 = min(e0 + CHUNK, E);
    const int nv = (e1 - e0) >> 2;
    const int4* c4 = (const int4*)(col + e0);
    const int4* r4 = (const int4*)(row + e0);
    const float4* w4 = (const float4*)(ew + e0);
    for (int i = t; i < nv; i += 1024) {
        const int4 c = c4[i];
        const int4 r = r4[i];
        const float4 w = w4[i];
        unsigned s0 = atomicAdd(&lh[c.x >> LGB], 1u);
        unsigned s1 = atomicAdd(&lh[c.y >> LGB], 1u);
        unsigned s2 = atomicAdd(&lh[c.z >> LGB], 1u);
        unsigned s3 = atomicAdd(&lh[c.w >> LGB], 1u);
        keysw[s0] = make_uint2(((unsigned)(c.x & (BKT - 1)) << ROWBITS) | (unsigned)r.x,
                               __float_as_uint(w.x));
        keysw[s1] = make_uint2(((unsigned)(c.y & (BKT - 1)) << ROWBITS) | (unsigned)r.y,
                               __float_as_uint(w.y));
        keysw[s2] = make_uint2(((unsigned)(c.z & (BKT - 1)) << ROWBITS) | (unsigned)r.z,
                               __float_as_uint(w.z));
        keysw[s3] = make_uint2(((unsigned)(c.w & (BKT - 1)) << ROWBITS) | (unsigned)r.w,
                               __float_as_uint(w.w));
    }
    for (int e = e0 + (nv << 2) + t; e < e1; e += 1024) {
        const int c = col[e];
        const unsigned slot = atomicAdd(&lh[c >> LGB], 1u);
        keysw[slot] = make_uint2(((unsigned)(c & (BKT - 1)) << ROWBITS) | (unsigned)row[e],
                                 __float_as_uint(ew[e]));
    }
}

// ---------------- Kernel 3: per-bucket degree from binned edges -> dis ----------------
__global__ __launch_bounds__(256) void degdis_kernel(const unsigned* __restrict__ base,
                                                     const uint2* __restrict__ keysw,
                                                     float* __restrict__ dis, int N) {
    __shared__ unsigned degf[BKT];
    const int t = threadIdx.x;
    degf[t] = 0;
    __syncthreads();
    const int b = blockIdx.x;
    const unsigned e0 = base[b], e1 = base[b + 1];
    for (unsigned e = e0 + t; e < e1; e += 256) {
        const uint2 kw = keysw[e];
        atomicAdd(&degf[kw.x >> ROWBITS], (unsigned)(__uint_as_float(kw.y) * FIXS));
    }
    __syncthreads();
    const int n = b * BKT + t;
    if (n < N)
        dis[n] = rsqrtf((float)degf[t] * (1.0f / FIXS) + 1.0f);  // +1 = self-loop
}

// ---------------- Kernel 4: x = h@W; yp = half(x * dis), padded to 32 ----------------
__global__ __launch_bounds__(256) void gemm_kernel(const float* __restrict__ h,
                                                   const float* __restrict__ W,
                                                   const float* __restrict__ dis,
                                                   uint4* __restrict__ yp4, int N) {
    __shared__ float hs[256 * D];
    __shared__ float Ws[D * D];
    const int t = threadIdx.x;
    const int nb = blockIdx.x * 256;
    const int cnt = min(256, N - nb);
    const int total = cnt * D;

    for (int i = t; i < D * D; i += 256) Ws[i] = W[i];
    for (int i = t; i < total; i += 256) hs[i] = h[nb * D + i];
    __syncthreads();

    float x[D];
    float dv = 0.f;
    if (t < cnt) {
#pragma unroll
        for (int j = 0; j < D; ++j) x[j] = 0.f;
#pragma unroll
        for (int k = 0; k < D; ++k) {
            const float hv = hs[t * D + k];
#pragma unroll
            for (int j = 0; j < D; ++j) x[j] += hv * Ws[k * D + j];
        }
        dv = dis[nb + t];
    }
    __syncthreads();
    __half* hsh = (__half*)hs;   // reuse LDS as half[256][32]
    if (t < cnt) {
#pragma unroll
        for (int j = 0; j < D; ++j) hsh[t * 32 + j] = __float2half_rn(x[j] * dv);
        hsh[t * 32 + 30] = __float2half_rn(0.f);
        hsh[t * 32 + 31] = __float2half_rn(0.f);
    }
    __syncthreads();
    const uint4* hv4 = (const uint4*)hs;
    for (int i = t; i < cnt * 4; i += 256) yp4[nb * 4 + i] = hv4[i];
}

// ---------------- Kernel 5: bucket aggregation via native int LDS atomics + fused MLP ----------------
__global__ __launch_bounds__(1024) void aggmlp_kernel(const uint4* __restrict__ yp4,
                                                      const float* __restrict__ dis,
                                                      const unsigned* __restrict__ base,
                                                      const uint2* __restrict__ keysw,
                                                      const float* __restrict__ convb,
                                                      const float* __restrict__ w1,
                                                      const float* __restrict__ b1,
                                                      const float* __restrict__ w2,
                                                      const float* __restrict__ b2,
                                                      const float* __restrict__ w3,
                                                      const float* __restrict__ b3,
                                                      const float* __restrict__ w4,
                                                      const float* __restrict__ b4,
                                                      float* __restrict__ out, int N) {
    __shared__ int acci[BKT * 32];   // fixed-point accumulator, XOR-swizzled (32 KB)
    __shared__ float cb[D];
    __shared__ float W1[300], B1[10], W2[100], B2[10], W3[100], B3[10], W4[10], B4v[1];
    const int t = threadIdx.x;
    if (t < D) cb[t] = convb[t];
    if (t < 300) W1[t] = w1[t];
    if (t < 100) W2[t] = w2[t];
    if (t >= 128 && t < 228) W3[t - 128] = w3[t - 128];
    if (t < 10) { B1[t] = b1[t]; B2[t] = b2[t]; B3[t] = b3[t]; W4[t] = w4[t]; }
    if (t == 0) B4v[0] = b4[0];

    const int b = blockIdx.x;
    const int nb = b * BKT;
    const int cnt = min(BKT, N - nb);

    // self-loop init: acc = fix(y_self)   (swizzled, no atomics needed)
    for (int i = t; i < cnt * 4; i += 1024) {
        const int n = i >> 2, q = i & 3;
        const uint4 v = yp4[(size_t)(nb + n) * 4 + q];
        const __half2* hh = (const __half2*)&v;
        const float2 f0 = __half22float2(hh[0]);
        const float2 f1 = __half22float2(hh[1]);
        const float2 f2 = __half22float2(hh[2]);
        const float2 f3 = __half22float2(hh[3]);
        const int bo = n << 5, sw = (n & 7) << 2, wb = q << 3;
        acci[bo + ((wb + 0) ^ sw)] = __float2int_rn(f0.x * FIXA);
        acci[bo + ((wb + 1) ^ sw)] = __float2int_rn(f0.y * FIXA);
        acci[bo + ((wb + 2) ^ sw)] = __float2int_rn(f1.x * FIXA);
        acci[bo + ((wb + 3) ^ sw)] = __float2int_rn(f1.y * FIXA);
        acci[bo + ((wb + 4) ^ sw)] = __float2int_rn(f2.x * FIXA);
        acci[bo + ((wb + 5) ^ sw)] = __float2int_rn(f2.y * FIXA);
        acci[bo + ((wb + 6) ^ sw)] = __float2int_rn(f3.x * FIXA);
        acci[bo + ((wb + 7) ^ sw)] = __float2int_rn(f3.y * FIXA);
    }
    __syncthreads();

    const unsigned e0v = base[b], e1v = base[b + 1];
    const int m = (int)(e1v - e0v) * 4;   // 4 lanes per edge

#define EDGE(kw, q)                                                                  \
    {                                                                                \
        const float wf = __uint_as_float((kw).y) * FIXA;                             \
        const uint4 v = yp4[(size_t)((kw).x & ROWMASK) * 4 + (q)];                   \
        const __half2* hh = (const __half2*)&v;                                      \
        const float2 f0 = __half22float2(hh[0]);                                     \
        const float2 f1 = __half22float2(hh[1]);                                     \
        const float2 f2 = __half22float2(hh[2]);                                     \
        const float2 f3 = __half22float2(hh[3]);                                     \
        const int loc = (int)((kw).x >> ROWBITS);                                    \
        const int bo = loc << 5;                                                     \
        const int sw = (loc & 7) << 2;                                               \
        const int wb = (q) << 3;                                                     \
        atomicAdd(&acci[bo + ((wb + 0) ^ sw)], __float2int_rn(f0.x * wf));           \
        atomicAdd(&acci[bo + ((wb + 1) ^ sw)], __float2int_rn(f0.y * wf));           \
        atomicAdd(&acci[bo + ((wb + 2) ^ sw)], __float2int_rn(f1.x * wf));           \
        atomicAdd(&acci[bo + ((wb + 3) ^ sw)], __float2int_rn(f1.y * wf));           \
        atomicAdd(&acci[bo + ((wb + 4) ^ sw)], __float2int_rn(f2.x * wf));           \
        atomicAdd(&acci[bo + ((wb + 5) ^ sw)], __float2int_rn(f2.y * wf));           \
        atomicAdd(&acci[bo + ((wb + 6) ^ sw)], __float2int_rn(f3.x * wf));           \
        atomicAdd(&acci[bo + ((wb + 7) ^ sw)], __float2int_rn(f3.y * wf));           \
    }

    for (int i = t; i < m; i += 2048) {
        const int iB = i + 1024;
        const uint2 kwA = keysw[e0v + (unsigned)(i >> 2)];
        const int qA = i & 3;
        if (iB < m) {
            const uint2 kwB = keysw[e0v + (unsigned)(iB >> 2)];
            const int qB = iB & 3;
            EDGE(kwA, qA)
            EDGE(kwB, qB)
        } else {
            EDGE(kwA, qA)
        }
    }
    __syncthreads();

    if (t < cnt) {
        const int nn = nb + t;
        const float dv = dis[nn] * (1.0f / FIXA);   // fold fixed-point descale into dis
        const int bo = t << 5;
        const int sw = (t & 7) << 2;
        float v[D];
#pragma unroll
        for (int j = 0; j < D; ++j)
            v[j] = fmaxf(dv * (float)acci[bo + (j ^ sw)] + cb[j], 0.f);
        float h1[10];
#pragma unroll
        for (int j = 0; j < 10; ++j) h1[j] = B1[j];
#pragma unroll
        for (int k = 0; k < D; ++k) {
            const float vv = v[k];
#pragma unroll
            for (int j = 0; j < 10; ++j) h1[j] += vv * W1[k * 10 + j];
        }
#pragma unroll
        for (int j = 0; j < 10; ++j) h1[j] = fmaxf(h1[j], 0.f);
        float h2[10];
#pragma unroll
        for (int j = 0; j < 10; ++j) h2[j] = B2[j];
#pragma unroll
        for (int k = 0; k < 10; ++k) {
            const float vv = h1[k];
#pragma unroll
            for (int j = 0; j < 10; ++j) h2[j] += vv * W2[k * 10 + j];
        }
#pragma unroll
        for (int j = 0; j < 10; ++j) h2[j] = fmaxf(h2[j], 0.f);
        float h3[10];
#pragma unroll
        for (int j = 0; j < 10; ++j) h3[j] = B3[j];
#pragma unroll
        for (int k = 0; k < 10; ++k) {
            const float vv = h2[k];
#pragma unroll
            for (int j = 0; j < 10; ++j) h3[j] += vv * W3[k * 10 + j];
        }
#pragma unroll
        for (int j = 0; j < 10; ++j) h3[j] = fmaxf(h3[j], 0.f);
        float z = B4v[0];
#pragma unroll
        for (int k = 0; k < 10; ++k) z += h3[k] * W4[k];
        out[nn] = 1.f / (1.f + expf(-z));
    }
}

extern "C" void kernel_launch(void* const* d_in, const int* in_sizes, int n_in,
                              void* d_out, int out_size, void* d_ws, size_t ws_size,
                              hipStream_t stream) {
    const float* h   = (const float*)d_in[0];
    const int*   ei  = (const int*)d_in[1];   // [2, E]: row = ei[0:E], col = ei[E:2E]
    const float* ew  = (const float*)d_in[2];
    const float* convW = (const float*)d_in[3];
    const float* convb = (const float*)d_in[4];
    const float* w1 = (const float*)d_in[5];
    const float* b1 = (const float*)d_in[6];
    const float* w2 = (const float*)d_in[7];
    const float* b2 = (const float*)d_in[8];
    const float* w3 = (const float*)d_in[9];
    const float* b3 = (const float*)d_in[10];
    const float* w4 = (const float*)d_in[11];
    const float* b4 = (const float*)d_in[12];
    float* out = (float*)d_out;

    const int N = in_sizes[0] / D;
    const int E = in_sizes[2];
    const int* row = ei;
    const int* col = ei + E;

    const int nbkt = (N + BKT - 1) >> LGB;        // 391 for N=100000
    const int nchunks = (E + CHUNK - 1) / CHUNK;  // 391
    const int M = nchunks * nbkt;                 // 152881
    const int ntiles = (M + 1023) >> 10;          // 150 (must be <= 1024)
    const int nblk256 = (N + 255) / 256;          // gemm blocks

    // workspace: yp[N*32 half] | keysw[E uint2] | dis[N] | cnt[M] | base[nbkt+1] | psum[ntiles]
    __half* yp = (__half*)d_ws;
    uint2* keysw = (uint2*)(yp + (size_t)N * 32);
    float* dis = (float*)(keysw + E);
    unsigned* cntm = (unsigned*)(dis + N);
    unsigned* base = cntm + M;
    unsigned* psum = base + (nbkt + 1);

    count_kernel<<<nchunks, 1024, 0, stream>>>(col, cntm, E, nbkt);
    scanA_kernel<<<ntiles, 1024, 0, stream>>>(cntm, psum, nchunks, nbkt, M);
    scanB_kernel<<<1, 1024, 0, stream>>>(psum, ntiles);
    scanC_kernel<<<ntiles, 1024, 0, stream>>>(cntm, psum, base, nchunks, nbkt, M, E);
    scatter_kernel<<<nchunks, 1024, 0, stream>>>(row, col, ew, cntm, keysw, E, nbkt);
    degdis_kernel<<<nbkt, 256, 0, stream>>>(base, keysw, dis, N);
    gemm_kernel<<<nblk256, 256, 0, stream>>>(h, convW, dis, (uint4*)yp, N);
    aggmlp_kernel<<<nbkt, 1024, 0, stream>>>((const uint4*)yp, dis, base, keysw, convb,
                                             w1, b1, w2, b2, w3, b3, w4, b4, out, N);
}

// Round 9
// 121.767 us; speedup vs baseline: 7.3492x; 1.0537x over previous
//
#include <hip/hip_runtime.h>
#include <hip/hip_fp16.h>
#include <math.h>

#define D 30
#define FIXS 16777216.0f     // 2^24 fixed-point scale for degree weights
#define FIXA 1048576.0f      // 2^20 fixed-point scale for feature aggregation
#define BKT 128              // destination nodes per bucket
#define LGB 7
#define CHUNK 8192           // edges per chunk
#define ROWBITS 18
#define ROWMASK ((1u << ROWBITS) - 1)
#define MAXBKT 1024

// ---------------- Kernel 1: per-(chunk,bucket) counts ----------------
__global__ __launch_bounds__(1024) void count_kernel(const int* __restrict__ col,
                                                     unsigned* __restrict__ cnt,
                                                     int E, int nbkt) {
    __shared__ unsigned lh[MAXBKT];
    const int t = threadIdx.x;
    for (int i = t; i < nbkt; i += 1024) lh[i] = 0;
    __syncthreads();
    const int e0 = blockIdx.x * CHUNK;
    const int e1 = min(e0 + CHUNK, E);
    const int nv = (e1 - e0) >> 2;
    const int4* c4 = (const int4*)(col + e0);
    for (int i = t; i < nv; i += 1024) {
        const int4 c = c4[i];
        atomicAdd(&lh[c.x >> LGB], 1u);
        atomicAdd(&lh[c.y >> LGB], 1u);
        atomicAdd(&lh[c.z >> LGB], 1u);
        atomicAdd(&lh[c.w >> LGB], 1u);
    }
    for (int e = e0 + (nv << 2) + t; e < e1; e += 1024) atomicAdd(&lh[col[e] >> LGB], 1u);
    __syncthreads();
    unsigned* dst = cnt + (size_t)blockIdx.x * nbkt;
    for (int i = t; i < nbkt; i += 1024) dst[i] = lh[i];
}

// ---------------- Scan A: tile-wise exclusive scan in bucket-major order ----------------
// scan index i = b*nchunks + c  <->  storage s = c*nbkt + b (bijective, blocks disjoint)
__global__ __launch_bounds__(1024) void scanA_kernel(unsigned* __restrict__ cnt,
                                                     unsigned* __restrict__ psum,
                                                     int nchunks, int nbkt, int M) {
    __shared__ unsigned s[1024];
    const int t = threadIdx.x;
    const int i = blockIdx.x * 1024 + t;
    unsigned v = 0;
    int sidx = 0;
    if (i < M) {
        const int b = i / nchunks;
        const int c = i - b * nchunks;
        sidx = c * nbkt + b;
        v = cnt[sidx];
    }
    s[t] = v;
    for (int off = 1; off < 1024; off <<= 1) {
        __syncthreads();
        const unsigned x = (t >= off) ? s[t - off] : 0u;
        __syncthreads();
        s[t] += x;
    }
    __syncthreads();
    if (i < M) cnt[sidx] = s[t] - v;          // exclusive within tile
    if (t == 1023) psum[blockIdx.x] = s[1023];
}

// ---------------- Scan B: exclusive scan of tile sums (1 block) ----------------
__global__ __launch_bounds__(1024) void scanB_kernel(unsigned* __restrict__ psum, int nt) {
    __shared__ unsigned s[1024];
    const int t = threadIdx.x;
    const unsigned v = (t < nt) ? psum[t] : 0u;
    s[t] = v;
    for (int off = 1; off < 1024; off <<= 1) {
        __syncthreads();
        const unsigned x = (t >= off) ? s[t - off] : 0u;
        __syncthreads();
        s[t] += x;
    }
    __syncthreads();
    if (t < nt) psum[t] = s[t] - v;
}

// ---------------- Scan C: add tile offsets; emit per-bucket base ----------------
__global__ __launch_bounds__(1024) void scanC_kernel(unsigned* __restrict__ cnt,
                                                     const unsigned* __restrict__ psum,
                                                     unsigned* __restrict__ base,
                                                     int nchunks, int nbkt, int M, int E_) {
    const int i = blockIdx.x * 1024 + threadIdx.x;
    if (i < M) {
        const int b = i / nchunks;
        const int c = i - b * nchunks;
        const unsigned val = cnt[c * nbkt + b] + psum[blockIdx.x];
        cnt[c * nbkt + b] = val;
        if (c == 0) base[b] = val;
    }
    if (i == 0) base[nbkt] = (unsigned)E_;
}

// ---------------- Kernel 2: scatter edges to sorted positions (no global atomics) ----------------
__global__ __launch_bounds__(1024) void scatter_kernel(const int* __restrict__ row,
                                                       const int* __restrict__ col,
                                                       const float* __restrict__ ew,
                                                       const unsigned* __restrict__ cnt,
                                                       uint2* __restrict__ keysw,
                                                       int E, int nbkt) {
    __shared__ unsigned lh[MAXBKT];
    const int t = threadIdx.x;
    const unsigned* src = cnt + (size_t)blockIdx.x * nbkt;
    for (int i = t; i < nbkt; i += 1024) lh[i] = src[i];
    __syncthreads();
    const int e0 = blockIdx.x * CHUNK;
    const int e1 = min(e0 + CHUNK, E);
    const int nv = (e1 - e0) >> 2;
    const int4* c4 = (const int4*)(col + e0);
    const int4* r4 = (const int4*)(row + e0);
    const float4* w4 = (const float4*)(ew + e0);
    for (int i = t; i < nv; i += 1024) {
        const int4 c = c4[i];
        const int4 r = r4[i];
        const float4 w = w4[i];
        unsigned s0 = atomicAdd(&lh[c.x >> LGB], 1u);
        unsigned s1 = atomicAdd(&lh[c.y >> LGB], 1u);
        unsigned s2 = atomicAdd(&lh[c.z >> LGB], 1u);
        unsigned s3 = atomicAdd(&lh[c.w >> LGB], 1u);
        keysw[s0] = make_uint2(((unsigned)(c.x & (BKT - 1)) << ROWBITS) | (unsigned)r.x,
                               __float_as_uint(w.x));
        keysw[s1] = make_uint2(((unsigned)(c.y & (BKT - 1)) << ROWBITS) | (unsigned)r.y,
                               __float_as_uint(w.y));
        keysw[s2] = make_uint2(((unsigned)(c.z & (BKT - 1)) << ROWBITS) | (unsigned)r.z,
                               __float_as_uint(w.z));
        keysw[s3] = make_uint2(((unsigned)(c.w & (BKT - 1)) << ROWBITS) | (unsigned)r.w,
                               __float_as_uint(w.w));
    }
    for (int e = e0 + (nv << 2) + t; e < e1; e += 1024) {
        const int c = col[e];
        const unsigned slot = atomicAdd(&lh[c >> LGB], 1u);
        keysw[slot] = make_uint2(((unsigned)(c & (BKT - 1)) << ROWBITS) | (unsigned)row[e],
                                 __float_as_uint(ew[e]));
    }
}

// ---------------- Kernel 3: per-bucket degree from binned edges -> dis ----------------
__global__ __launch_bounds__(256) void degdis_kernel(const unsigned* __restrict__ base,
                                                     const uint2* __restrict__ keysw,
                                                     float* __restrict__ dis, int N) {
    __shared__ unsigned degf[BKT];
    const int t = threadIdx.x;
    if (t < BKT) degf[t] = 0;
    __syncthreads();
    const int b = blockIdx.x;
    const unsigned e0 = base[b], e1 = base[b + 1];
    for (unsigned e = e0 + t; e < e1; e += 256) {
        const uint2 kw = keysw[e];
        atomicAdd(&degf[kw.x >> ROWBITS], (unsigned)(__uint_as_float(kw.y) * FIXS));
    }
    __syncthreads();
    const int n = b * BKT + t;
    if (t < BKT && n < N)
        dis[n] = rsqrtf((float)degf[t] * (1.0f / FIXS) + 1.0f);  // +1 = self-loop
}

// ---------------- Kernel 4: x = h@W; yp = half(x * dis), padded to 32 ----------------
__global__ __launch_bounds__(256) void gemm_kernel(const float* __restrict__ h,
                                                   const float* __restrict__ W,
                                                   const float* __restrict__ dis,
                                                   uint4* __restrict__ yp4, int N) {
    __shared__ float hs[256 * D];
    __shared__ float Ws[D * D];
    const int t = threadIdx.x;
    const int nb = blockIdx.x * 256;
    const int cnt = min(256, N - nb);
    const int total = cnt * D;

    for (int i = t; i < D * D; i += 256) Ws[i] = W[i];
    for (int i = t; i < total; i += 256) hs[i] = h[nb * D + i];
    __syncthreads();

    float x[D];
    float dv = 0.f;
    if (t < cnt) {
#pragma unroll
        for (int j = 0; j < D; ++j) x[j] = 0.f;
#pragma unroll
        for (int k = 0; k < D; ++k) {
            const float hv = hs[t * D + k];
#pragma unroll
            for (int j = 0; j < D; ++j) x[j] += hv * Ws[k * D + j];
        }
        dv = dis[nb + t];
    }
    __syncthreads();
    __half* hsh = (__half*)hs;   // reuse LDS as half[256][32]
    if (t < cnt) {
#pragma unroll
        for (int j = 0; j < D; ++j) hsh[t * 32 + j] = __float2half_rn(x[j] * dv);
        hsh[t * 32 + 30] = __float2half_rn(0.f);
        hsh[t * 32 + 31] = __float2half_rn(0.f);
    }
    __syncthreads();
    const uint4* hv4 = (const uint4*)hs;
    for (int i = t; i < cnt * 4; i += 256) yp4[nb * 4 + i] = hv4[i];
}

// ---------------- Kernel 5: bucket aggregation via native int LDS atomics + fused MLP ----------------
// acci element j of node loc lives at (loc<<5) + (j ^ (loc&31)) -> full 32-bank spread
__global__ __launch_bounds__(512) void aggmlp_kernel(const uint4* __restrict__ yp4,
                                                     const float* __restrict__ dis,
                                                     const unsigned* __restrict__ base,
                                                     const uint2* __restrict__ keysw,
                                                     const float* __restrict__ convb,
                                                     const float* __restrict__ w1,
                                                     const float* __restrict__ b1,
                                                     const float* __restrict__ w2,
                                                     const float* __restrict__ b2,
                                                     const float* __restrict__ w3,
                                                     const float* __restrict__ b3,
                                                     const float* __restrict__ w4,
                                                     const float* __restrict__ b4,
                                                     float* __restrict__ out, int N) {
    __shared__ int acci[BKT * 32];   // fixed-point accumulator, 5-bit XOR swizzled (16 KB)
    __shared__ float cb[D];
    __shared__ float W1[300], B1[10], W2[100], B2[10], W3[100], B3[10], W4[10], B4v[1];
    const int t = threadIdx.x;
    if (t < D) cb[t] = convb[t];
    if (t < 300) W1[t] = w1[t];
    if (t < 100) W2[t] = w2[t];
    if (t >= 128 && t < 228) W3[t - 128] = w3[t - 128];
    if (t < 10) { B1[t] = b1[t]; B2[t] = b2[t]; B3[t] = b3[t]; W4[t] = w4[t]; }
    if (t == 0) B4v[0] = b4[0];

    const int b = blockIdx.x;
    const int nb = b * BKT;
    const int cnt = min(BKT, N - nb);

    // self-loop init: acc = fix(y_self)   (swizzled, no atomics needed)
    for (int i = t; i < cnt * 4; i += 512) {
        const int n = i >> 2, q = i & 3;
        const uint4 v = yp4[(size_t)(nb + n) * 4 + q];
        const __half2* hh = (const __half2*)&v;
        const float2 f0 = __half22float2(hh[0]);
        const float2 f1 = __half22float2(hh[1]);
        const float2 f2 = __half22float2(hh[2]);
        const float2 f3 = __half22float2(hh[3]);
        const int bo = n << 5, sw = n & 31, wb = q << 3;
        acci[bo + ((wb + 0) ^ sw)] = __float2int_rn(f0.x * FIXA);
        acci[bo + ((wb + 1) ^ sw)] = __float2int_rn(f0.y * FIXA);
        acci[bo + ((wb + 2) ^ sw)] = __float2int_rn(f1.x * FIXA);
        acci[bo + ((wb + 3) ^ sw)] = __float2int_rn(f1.y * FIXA);
        acci[bo + ((wb + 4) ^ sw)] = __float2int_rn(f2.x * FIXA);
        acci[bo + ((wb + 5) ^ sw)] = __float2int_rn(f2.y * FIXA);
        acci[bo + ((wb + 6) ^ sw)] = __float2int_rn(f3.x * FIXA);
        acci[bo + ((wb + 7) ^ sw)] = __float2int_rn(f3.y * FIXA);
    }
    __syncthreads();

    const unsigned e0v = base[b], e1v = base[b + 1];
    const int m = (int)(e1v - e0v) * 4;   // 4 lanes per edge

#define EDGE(kw, q)                                                                  \
    {                                                                                \
        const float wf = __uint_as_float((kw).y) * FIXA;                             \
        const uint4 v = yp4[(size_t)((kw).x & ROWMASK) * 4 + (q)];                   \
        const __half2* hh = (const __half2*)&v;                                      \
        const float2 f0 = __half22float2(hh[0]);                                     \
        const float2 f1 = __half22float2(hh[1]);                                     \
        const float2 f2 = __half22float2(hh[2]);                                     \
        const float2 f3 = __half22float2(hh[3]);                                     \
        const int loc = (int)((kw).x >> ROWBITS);                                    \
        const int bo = loc << 5;                                                     \
        const int sw = loc & 31;                                                     \
        const int wb = (q) << 3;                                                     \
        atomicAdd(&acci[bo + ((wb + 0) ^ sw)], __float2int_rn(f0.x * wf));           \
        atomicAdd(&acci[bo + ((wb + 1) ^ sw)], __float2int_rn(f0.y * wf));           \
        atomicAdd(&acci[bo + ((wb + 2) ^ sw)], __float2int_rn(f1.x * wf));           \
        atomicAdd(&acci[bo + ((wb + 3) ^ sw)], __float2int_rn(f1.y * wf));           \
        atomicAdd(&acci[bo + ((wb + 4) ^ sw)], __float2int_rn(f2.x * wf));           \
        atomicAdd(&acci[bo + ((wb + 5) ^ sw)], __float2int_rn(f2.y * wf));           \
        atomicAdd(&acci[bo + ((wb + 6) ^ sw)], __float2int_rn(f3.x * wf));           \
        atomicAdd(&acci[bo + ((wb + 7) ^ sw)], __float2int_rn(f3.y * wf));           \
    }

    for (int i = t; i < m; i += 1024) {
        const int iB = i + 512;
        const uint2 kwA = keysw[e0v + (unsigned)(i >> 2)];
        const int qA = i & 3;
        if (iB < m) {
            const uint2 kwB = keysw[e0v + (unsigned)(iB >> 2)];
            const int qB = iB & 3;
            EDGE(kwA, qA)
            EDGE(kwB, qB)
        } else {
            EDGE(kwA, qA)
        }
    }
    __syncthreads();

    if (t < cnt) {
        const int nn = nb + t;
        const float dv = dis[nn] * (1.0f / FIXA);   // fold fixed-point descale into dis
        const int bo = t << 5;
        const int sw = t & 31;
        float v[D];
#pragma unroll
        for (int j = 0; j < D; ++j)
            v[j] = fmaxf(dv * (float)acci[bo + (j ^ sw)] + cb[j], 0.f);
        float h1[10];
#pragma unroll
        for (int j = 0; j < 10; ++j) h1[j] = B1[j];
#pragma unroll
        for (int k = 0; k < D; ++k) {
            const float vv = v[k];
#pragma unroll
            for (int j = 0; j < 10; ++j) h1[j] += vv * W1[k * 10 + j];
        }
#pragma unroll
        for (int j = 0; j < 10; ++j) h1[j] = fmaxf(h1[j], 0.f);
        float h2[10];
#pragma unroll
        for (int j = 0; j < 10; ++j) h2[j] = B2[j];
#pragma unroll
        for (int k = 0; k < 10; ++k) {
            const float vv = h1[k];
#pragma unroll
            for (int j = 0; j < 10; ++j) h2[j] += vv * W2[k * 10 + j];
        }
#pragma unroll
        for (int j = 0; j < 10; ++j) h2[j] = fmaxf(h2[j], 0.f);
        float h3[10];
#pragma unroll
        for (int j = 0; j < 10; ++j) h3[j] = B3[j];
#pragma unroll
        for (int k = 0; k < 10; ++k) {
            const float vv = h2[k];
#pragma unroll
            for (int j = 0; j < 10; ++j) h3[j] += vv * W3[k * 10 + j];
        }
#pragma unroll
        for (int j = 0; j < 10; ++j) h3[j] = fmaxf(h3[j], 0.f);
        float z = B4v[0];
#pragma unroll
        for (int k = 0; k < 10; ++k) z += h3[k] * W4[k];
        out[nn] = 1.f / (1.f + expf(-z));
    }
}

extern "C" void kernel_launch(void* const* d_in, const int* in_sizes, int n_in,
                              void* d_out, int out_size, void* d_ws, size_t ws_size,
                              hipStream_t stream) {
    const float* h   = (const float*)d_in[0];
    const int*   ei  = (const int*)d_in[1];   // [2, E]: row = ei[0:E], col = ei[E:2E]
    const float* ew  = (const float*)d_in[2];
    const float* convW = (const float*)d_in[3];
    const float* convb = (const float*)d_in[4];
    const float* w1 = (const float*)d_in[5];
    const float* b1 = (const float*)d_in[6];
    const float* w2 = (const float*)d_in[7];
    const float* b2 = (const float*)d_in[8];
    const float* w3 = (const float*)d_in[9];
    const float* b3 = (const float*)d_in[10];
    const float* w4 = (const float*)d_in[11];
    const float* b4 = (const float*)d_in[12];
    float* out = (float*)d_out;

    const int N = in_sizes[0] / D;
    const int E = in_sizes[2];
    const int* row = ei;
    const int* col = ei + E;

    const int nbkt = (N + BKT - 1) >> LGB;        // 782 for N=100000
    const int nchunks = (E + CHUNK - 1) / CHUNK;  // 391
    const int M = nchunks * nbkt;                 // 305762
    const int ntiles = (M + 1023) >> 10;          // 299 (must be <= 1024)
    const int nblk256 = (N + 255) / 256;          // gemm blocks

    // workspace: yp[N*32 half] | keysw[E uint2] | dis[N] | cnt[M] | base[nbkt+1] | psum[ntiles]
    __half* yp = (__half*)d_ws;
    uint2* keysw = (uint2*)(yp + (size_t)N * 32);
    float* dis = (float*)(keysw + E);
    unsigned* cntm = (unsigned*)(dis + N);
    unsigned* base = cntm + M;
    unsigned* psum = base + (nbkt + 1);

    count_kernel<<<nchunks, 1024, 0, stream>>>(col, cntm, E, nbkt);
    scanA_kernel<<<ntiles, 1024, 0, stream>>>(cntm, psum, nchunks, nbkt, M);
    scanB_kernel<<<1, 1024, 0, stream>>>(psum, ntiles);
    scanC_kernel<<<ntiles, 1024, 0, stream>>>(cntm, psum, base, nchunks, nbkt, M, E);
    scatter_kernel<<<nchunks, 1024, 0, stream>>>(row, col, ew, cntm, keysw, E, nbkt);
    degdis_kernel<<<nbkt, 256, 0, stream>>>(base, keysw, dis, N);
    gemm_kernel<<<nblk256, 256, 0, stream>>>(h, convW, dis, (uint4*)yp, N);
    aggmlp_kernel<<<nbkt, 512, 0, stream>>>((const uint4*)yp, dis, base, keysw, convb,
                                            w1, b1, w2, b2, w3, b3, w4, b4, out, N);
}